// Round 2
// baseline (919.079 us; speedup 1.0000x reference)
//
#include <hip/hip_runtime.h>

// Problem constants: G=64 graphs, P=1024 nodes/graph, D=64 feat, K=6 knn.
// N = 65536 nodes. All fp32.

typedef float4 f4;

#define COMPC(v, c) ((c)==0 ? (v).x : (c)==1 ? (v).y : (c)==2 ? (v).z : (v).w)

// 4x4 register-tile FMA: a0..a3 are float4 accumulators (rows), sv rows comp, wv cols comp
#define FMA16(sv, wv) do { \
  a0.x += (sv).x*(wv).x; a0.y += (sv).x*(wv).y; a0.z += (sv).x*(wv).z; a0.w += (sv).x*(wv).w; \
  a1.x += (sv).y*(wv).x; a1.y += (sv).y*(wv).y; a1.z += (sv).y*(wv).z; a1.w += (sv).y*(wv).w; \
  a2.x += (sv).z*(wv).x; a2.y += (sv).z*(wv).y; a2.z += (sv).z*(wv).z; a2.w += (sv).z*(wv).w; \
  a3.x += (sv).w*(wv).x; a3.y += (sv).w*(wv).y; a3.z += (sv).w*(wv).z; a3.w += (sv).w*(wv).w; \
} while (0)

// sorted-ascending top-6 insertion, lexicographic (dist, idx) to match top_k tie-break
__device__ __forceinline__ void ins6(float s, int c, float (&D)[6], int (&I)[6]) {
  if (s < D[5] || (s == D[5] && c < I[5])) {
    D[5] = s; I[5] = c;
#pragma unroll
    for (int k = 5; k > 0; --k) {
      bool sw = (D[k] < D[k-1]) || (D[k] == D[k-1] && I[k] < I[k-1]);
      float lo = sw ? D[k]   : D[k-1];
      float hi = sw ? D[k-1] : D[k];
      int   li = sw ? I[k]   : I[k-1];
      int   hj = sw ? I[k-1] : I[k];
      D[k-1] = lo; D[k] = hi; I[k-1] = li; I[k] = hj;
    }
  }
}

// ---------------- squared norms: one wave (64 lanes) per row ----------------
__global__ void ksq(const float* __restrict__ x, float* __restrict__ sqn) {
  int gtid = blockIdx.x * 256 + threadIdx.x;
  int row = gtid >> 6;
  int lane = threadIdx.x & 63;
  float v = x[(size_t)row * 64 + lane];
  v *= v;
#pragma unroll
  for (int m = 32; m; m >>= 1) v += __shfl_xor(v, m, 64);
  if (lane == 0) sqn[row] = v;
}

// ---------------- KNN: block = 64 queries x 1024 candidates of one graph ---
__global__ __launch_bounds__(256) void kknn(const float* __restrict__ x,
                                            const float* __restrict__ sqn,
                                            int* __restrict__ nbr) {
  __shared__ float qT[64][68];            // queries transposed [d][q], padded
  __shared__ float cT[64][68];            // candidate chunk transposed
  __shared__ float sqc[64];
  __shared__ float mdist[64][97];         // merge buffer, stride 97 (bank-conflict-free)
  __shared__ unsigned short midx[64][97];

  const int g = blockIdx.x >> 4;
  const int qt = blockIdx.x & 15;
  const int qbase = g * 1024 + qt * 64;
  const int tid = threadIdx.x;
  const int il = tid >> 2, qq = tid & 3;

  // load 64-query tile -> transposed LDS (coalesced 64B per 4-lane group)
  {
    const f4* src = (const f4*)(x + (size_t)(qbase + il) * 64) + qq * 4;
#pragma unroll
    for (int m = 0; m < 4; ++m) {
      f4 v = src[m];
      int d0 = qq * 16 + m * 4;
      qT[d0+0][il] = v.x; qT[d0+1][il] = v.y; qT[d0+2][il] = v.z; qT[d0+3][il] = v.w;
    }
  }

  const int ti = tid & 15, tc = tid >> 4;
  const int qlbase = qt * 64 + 4 * ti;   // local query idx base (within graph)
  float dist[4][6]; int idxl[4][6];
#pragma unroll
  for (int r = 0; r < 4; ++r)
#pragma unroll
    for (int k = 0; k < 6; ++k) { dist[r][k] = 1e30f; idxl[r][k] = 0x7fffffff; }

  for (int ch = 0; ch < 16; ++ch) {
    __syncthreads();   // protect cT reuse
    const int cbase = g * 1024 + ch * 64;
    {
      const f4* src = (const f4*)(x + (size_t)(cbase + il) * 64) + qq * 4;
#pragma unroll
      for (int m = 0; m < 4; ++m) {
        f4 v = src[m];
        int d0 = qq * 16 + m * 4;
        cT[d0+0][il] = v.x; cT[d0+1][il] = v.y; cT[d0+2][il] = v.z; cT[d0+3][il] = v.w;
      }
      if (tid < 64) sqc[tid] = sqn[cbase + tid];
    }
    __syncthreads();

    f4 a0 = {0.f,0.f,0.f,0.f}, a1 = a0, a2 = a0, a3 = a0;
#pragma unroll 16
    for (int d = 0; d < 64; ++d) {
      f4 qv = *(const f4*)&qT[d][4*ti];
      f4 cv = *(const f4*)&cT[d][4*tc];
      FMA16(qv, cv);
    }

    const int cl0 = ch * 64 + 4 * tc;
#define SELC(c) { \
      const int cl = cl0 + (c); \
      const float sqv = sqc[4*tc + (c)]; \
      float s; \
      s = sqv - 2.f*COMPC(a0,(c)); if (qlbase+0 != cl) ins6(s, cl, dist[0], idxl[0]); \
      s = sqv - 2.f*COMPC(a1,(c)); if (qlbase+1 != cl) ins6(s, cl, dist[1], idxl[1]); \
      s = sqv - 2.f*COMPC(a2,(c)); if (qlbase+2 != cl) ins6(s, cl, dist[2], idxl[2]); \
      s = sqv - 2.f*COMPC(a3,(c)); if (qlbase+3 != cl) ins6(s, cl, dist[3], idxl[3]); }
    SELC(0) SELC(1) SELC(2) SELC(3)
#undef SELC
  }

  // dump per-thread top-6 lists and merge 16 lists per query
#pragma unroll
  for (int r = 0; r < 4; ++r)
#pragma unroll
    for (int k = 0; k < 6; ++k) {
      mdist[4*ti+r][tc*6+k] = dist[r][k];
      midx [4*ti+r][tc*6+k] = (unsigned short)idxl[r][k];
    }
  __syncthreads();
  if (tid < 64) {
    float D[6]; int I[6];
#pragma unroll
    for (int k = 0; k < 6; ++k) { D[k] = 1e30f; I[k] = 0x7fffffff; }
    for (int t = 0; t < 16; ++t)
#pragma unroll
      for (int k = 0; k < 6; ++k) ins6(mdist[tid][t*6+k], (int)midx[tid][t*6+k], D, I);
#pragma unroll
    for (int k = 0; k < 6; ++k) nbr[(size_t)(qbase + tid) * 6 + k] = g * 1024 + I[k];
  }
}

// ---------------- pre_nn: two fused 64x64 GEMMs + PReLU, 64 rows per block --
__global__ __launch_bounds__(256) void kpre(const float* __restrict__ x,
    const float* __restrict__ W1, const float* __restrict__ b1, const float* __restrict__ p1,
    const float* __restrict__ W2, const float* __restrict__ b2, const float* __restrict__ p2,
    float* __restrict__ hpre) {
  __shared__ float xT[64][68];
  __shared__ float yT[64][68];
  __shared__ float W1l[64][64];
  __shared__ float W2l[64][64];
  __shared__ float bb1[64], aa1[64], bb2[64], aa2[64];
  const int tid = threadIdx.x;
  const int base = blockIdx.x * 64;
#pragma unroll
  for (int k = 0; k < 16; ++k) {
    int idx = tid + 256 * k;
    W1l[idx >> 6][idx & 63] = W1[idx];
    W2l[idx >> 6][idx & 63] = W2[idx];
  }
  if (tid < 64) { bb1[tid] = b1[tid]; aa1[tid] = p1[tid]; bb2[tid] = b2[tid]; aa2[tid] = p2[tid]; }
  const int il = tid >> 2, qq = tid & 3;
  {
    const f4* src = (const f4*)(x + (size_t)(base + il) * 64) + qq * 4;
#pragma unroll
    for (int m = 0; m < 4; ++m) {
      f4 v = src[m];
      int d0 = qq * 16 + m * 4;
      xT[d0+0][il] = v.x; xT[d0+1][il] = v.y; xT[d0+2][il] = v.z; xT[d0+3][il] = v.w;
    }
  }
  __syncthreads();
  const int ti = tid & 15, to = tid >> 4;
  f4 a0 = {0.f,0.f,0.f,0.f}, a1 = a0, a2 = a0, a3 = a0;
#pragma unroll 16
  for (int d = 0; d < 64; ++d) {
    f4 sv = *(const f4*)&xT[d][4*ti];
    f4 wv = *(const f4*)&W1l[d][4*to];
    FMA16(sv, wv);
  }
#define EPI1(AR, r) { \
    const int row = 4*ti + (r); float v; \
    v = AR.x + bb1[4*to+0]; v = v >= 0.f ? v : aa1[4*to+0]*v; yT[4*to+0][row] = v; \
    v = AR.y + bb1[4*to+1]; v = v >= 0.f ? v : aa1[4*to+1]*v; yT[4*to+1][row] = v; \
    v = AR.z + bb1[4*to+2]; v = v >= 0.f ? v : aa1[4*to+2]*v; yT[4*to+2][row] = v; \
    v = AR.w + bb1[4*to+3]; v = v >= 0.f ? v : aa1[4*to+3]*v; yT[4*to+3][row] = v; }
  EPI1(a0, 0) EPI1(a1, 1) EPI1(a2, 2) EPI1(a3, 3)
#undef EPI1
  __syncthreads();
  a0.x=a0.y=a0.z=a0.w=0.f; a1=a0; a2=a0; a3=a0;
#pragma unroll 16
  for (int d = 0; d < 64; ++d) {
    f4 sv = *(const f4*)&yT[d][4*ti];
    f4 wv = *(const f4*)&W2l[d][4*to];
    FMA16(sv, wv);
  }
#define EPI2(AR, r) { \
    const int i = base + 4*ti + (r); f4 ov; float v; \
    v = AR.x + bb2[4*to+0]; ov.x = v >= 0.f ? v : aa2[4*to+0]*v; \
    v = AR.y + bb2[4*to+1]; ov.y = v >= 0.f ? v : aa2[4*to+1]*v; \
    v = AR.z + bb2[4*to+2]; ov.z = v >= 0.f ? v : aa2[4*to+2]*v; \
    v = AR.w + bb2[4*to+3]; ov.w = v >= 0.f ? v : aa2[4*to+3]*v; \
    *((f4*)(hpre + (size_t)i * 64) + to) = ov; }
  EPI2(a0, 0) EPI2(a1, 1) EPI2(a2, 2) EPI2(a3, 3)
#undef EPI2
}

// ---------------- BN stats: per-feature sum / sumsq ------------------------
__global__ void kstats(const float* __restrict__ h, float* __restrict__ gsum,
                       float* __restrict__ gsq) {
  __shared__ float r1[256], r2[256];
  const int tid = threadIdx.x;
  const int f = tid & 63, sub = tid >> 6;
  const size_t rbase = (size_t)blockIdx.x * 256 + sub;
  float s = 0.f, s2 = 0.f;
  for (int k = 0; k < 64; ++k) {
    float v = h[(rbase + 4 * k) * 64 + f];
    s += v; s2 += v * v;
  }
  r1[tid] = s; r2[tid] = s2;
  __syncthreads();
  if (tid < 64) {
    s  = r1[tid] + r1[tid+64] + r1[tid+128] + r1[tid+192];
    s2 = r2[tid] + r2[tid+64] + r2[tid+128] + r2[tid+192];
    atomicAdd(&gsum[tid], s);
    atomicAdd(&gsq[tid], s2);
  }
}

__global__ void kfin(const float* __restrict__ gsum, const float* __restrict__ gsq,
                     const float* __restrict__ gamma, const float* __restrict__ beta,
                     float* __restrict__ scale, float* __restrict__ shift) {
  int f = threadIdx.x;
  float mu = gsum[f] * (1.f / 65536.f);
  float var = gsq[f] * (1.f / 65536.f) - mu * mu;
  float sc = gamma[f] * rsqrtf(var + 1e-5f);
  scale[f] = sc;
  shift[f] = beta[f] - mu * sc;
}

// ---------------- apply BN in place + pool stage 0 -------------------------
__global__ void kbn(float* __restrict__ h, const float* __restrict__ scale,
                    const float* __restrict__ shift, float* __restrict__ pooled) {
  __shared__ float red[256];
  const int tid = threadIdx.x;
  const int f = tid & 63, sub = tid >> 6;
  const size_t rbase = (size_t)blockIdx.x * 256 + sub;
  const int g = blockIdx.x >> 2;
  const float sc = scale[f], sh = shift[f];
  float acc = 0.f;
  for (int k = 0; k < 64; ++k) {
    size_t off = (rbase + 4 * k) * 64 + f;
    float v = h[off] * sc + sh;
    h[off] = v;
    acc += v;
  }
  red[tid] = acc;
  __syncthreads();
  if (tid < 64) {
    float t = red[tid] + red[tid+64] + red[tid+128] + red[tid+192];
    atomicAdd(&pooled[g * 320 + tid], t);
  }
}

// ---------------- one conv layer: gather-sum + GEMM + PReLU + pool ---------
__global__ __launch_bounds__(256) void kconv(const float* __restrict__ hIn,
    float* __restrict__ hOut, const int* __restrict__ nbr,
    const float* __restrict__ W, const float* __restrict__ bias,
    const float* __restrict__ act, float* __restrict__ pooled, int stageoff) {
  __shared__ float sT[64][68];
  __shared__ float Wl[64][64];
  __shared__ float bb[64], aa[64], pool[64];
  const int tid = threadIdx.x;
  const int base = blockIdx.x * 64;
  const int g = base >> 10;
#pragma unroll
  for (int k = 0; k < 16; ++k) { int idx = tid + 256 * k; Wl[idx >> 6][idx & 63] = W[idx]; }
  if (tid < 64) { bb[tid] = bias[tid]; aa[tid] = act[tid]; pool[tid] = 0.f; }

  // gather-sum of 6 neighbor rows -> transposed LDS
  const int il = tid >> 2, qq = tid & 3;
  {
    f4 acc0 = {0.f,0.f,0.f,0.f}, acc1 = acc0, acc2 = acc0, acc3 = acc0;
    const int i = base + il;
#pragma unroll
    for (int k = 0; k < 6; ++k) {
      int j = nbr[i * 6 + k];
      const f4* hj = (const f4*)(hIn + (size_t)j * 64) + qq * 4;
      f4 v0 = hj[0], v1 = hj[1], v2 = hj[2], v3 = hj[3];
      acc0.x += v0.x; acc0.y += v0.y; acc0.z += v0.z; acc0.w += v0.w;
      acc1.x += v1.x; acc1.y += v1.y; acc1.z += v1.z; acc1.w += v1.w;
      acc2.x += v2.x; acc2.y += v2.y; acc2.z += v2.z; acc2.w += v2.w;
      acc3.x += v3.x; acc3.y += v3.y; acc3.z += v3.z; acc3.w += v3.w;
    }
    const int d0 = qq * 16;
    sT[d0+ 0][il]=acc0.x; sT[d0+ 1][il]=acc0.y; sT[d0+ 2][il]=acc0.z; sT[d0+ 3][il]=acc0.w;
    sT[d0+ 4][il]=acc1.x; sT[d0+ 5][il]=acc1.y; sT[d0+ 6][il]=acc1.z; sT[d0+ 7][il]=acc1.w;
    sT[d0+ 8][il]=acc2.x; sT[d0+ 9][il]=acc2.y; sT[d0+10][il]=acc2.z; sT[d0+11][il]=acc2.w;
    sT[d0+12][il]=acc3.x; sT[d0+13][il]=acc3.y; sT[d0+14][il]=acc3.z; sT[d0+15][il]=acc3.w;
  }
  __syncthreads();

  const int ti = tid & 15, to = tid >> 4;
  f4 a0 = {0.f,0.f,0.f,0.f}, a1 = a0, a2 = a0, a3 = a0;
#pragma unroll 16
  for (int d = 0; d < 64; ++d) {
    f4 sv = *(const f4*)&sT[d][4*ti];
    f4 wv = *(const f4*)&Wl[d][4*to];
    FMA16(sv, wv);
  }

  const float bs0 = 6.f*bb[4*to+0], bs1 = 6.f*bb[4*to+1], bs2 = 6.f*bb[4*to+2], bs3 = 6.f*bb[4*to+3];
  const float av0 = aa[4*to+0], av1 = aa[4*to+1], av2 = aa[4*to+2], av3 = aa[4*to+3];
  float p0 = 0.f, pp1 = 0.f, pp2 = 0.f, pp3 = 0.f;
#define CEPI(AR, r) { \
    const int i = base + 4*ti + (r); \
    f4 res = *((const f4*)(hIn + (size_t)i * 64) + to); \
    f4 ov; float v; \
    v = AR.x + bs0 + res.x; v = v >= 0.f ? v : av0 * v; ov.x = v; p0  += v; \
    v = AR.y + bs1 + res.y; v = v >= 0.f ? v : av1 * v; ov.y = v; pp1 += v; \
    v = AR.z + bs2 + res.z; v = v >= 0.f ? v : av2 * v; ov.z = v; pp2 += v; \
    v = AR.w + bs3 + res.w; v = v >= 0.f ? v : av3 * v; ov.w = v; pp3 += v; \
    *((f4*)(hOut + (size_t)i * 64) + to) = ov; }
  CEPI(a0, 0) CEPI(a1, 1) CEPI(a2, 2) CEPI(a3, 3)
#undef CEPI
  atomicAdd(&pool[4*to+0], p0);
  atomicAdd(&pool[4*to+1], pp1);
  atomicAdd(&pool[4*to+2], pp2);
  atomicAdd(&pool[4*to+3], pp3);
  __syncthreads();
  if (tid < 64) atomicAdd(&pooled[g * 320 + stageoff + tid], pool[tid]);
}

// ---------------- FFN head: one block per graph ----------------------------
__global__ __launch_bounds__(256) void kffn(const float* __restrict__ pooled,
    const float* __restrict__ W1, const float* __restrict__ b1,
    const float* __restrict__ W2, const float* __restrict__ b2,
    float* __restrict__ out) {
  __shared__ float pg[320];
  __shared__ float z1[320];
  __shared__ float red[4];
  const int g = blockIdx.x, tid = threadIdx.x;
  for (int i = tid; i < 320; i += 256) pg[i] = pooled[g * 320 + i];
  __syncthreads();
  for (int o = tid; o < 320; o += 256) {
    float acc = b1[o];
    for (int d = 0; d < 320; ++d) acc += pg[d] * W1[d * 320 + o];
    z1[o] = acc >= 0.f ? acc : 0.01f * acc;
  }
  __syncthreads();
  float p = 0.f;
  for (int o = tid; o < 320; o += 256) p += z1[o] * W2[o];
#pragma unroll
  for (int m = 32; m; m >>= 1) p += __shfl_xor(p, m, 64);
  if ((tid & 63) == 0) red[tid >> 6] = p;
  __syncthreads();
  if (tid == 0) out[g] = red[0] + red[1] + red[2] + red[3] + b2[0];
}

extern "C" void kernel_launch(void* const* d_in, const int* in_sizes, int n_in,
                              void* d_out, int out_size, void* d_ws, size_t ws_size,
                              hipStream_t stream) {
  const float* x        = (const float*)d_in[0];
  const float* pre_W1   = (const float*)d_in[2];
  const float* pre_b1   = (const float*)d_in[3];
  const float* pre_a1   = (const float*)d_in[4];
  const float* pre_W2   = (const float*)d_in[5];
  const float* pre_b2   = (const float*)d_in[6];
  const float* pre_a2   = (const float*)d_in[7];
  const float* bn_gamma = (const float*)d_in[8];
  const float* bn_beta  = (const float*)d_in[9];
  const float* act_a    = (const float*)d_in[10];
  const float* conv_W   = (const float*)d_in[11];
  const float* conv_b   = (const float*)d_in[12];
  const float* ffn_W1   = (const float*)d_in[13];
  const float* ffn_b1   = (const float*)d_in[14];
  const float* ffn_W2   = (const float*)d_in[15];
  const float* ffn_b2   = (const float*)d_in[16];
  float* out = (float*)d_out;

  float* ws    = (float*)d_ws;
  float* hA    = ws;                         // N*64 = 4194304 floats
  float* hB    = ws + 4194304;               // N*64
  float* sqn   = ws + 8388608;               // N
  int*   nbr   = (int*)(ws + 8388608 + 65536);      // N*6 ints
  float* stats = ws + 8388608 + 65536 + 393216;     // 256 floats
  float* gsum  = stats;
  float* gsq   = stats + 64;
  float* scale = stats + 128;
  float* shift = stats + 192;
  float* pooled = stats + 256;               // 64*320 floats

  hipMemsetAsync(stats, 0, (256 + 64 * 320) * sizeof(float), stream);

  ksq   <<<16384, 256, 0, stream>>>(x, sqn);
  kknn  <<<1024, 256, 0, stream>>>(x, sqn, nbr);
  kpre  <<<1024, 256, 0, stream>>>(x, pre_W1, pre_b1, pre_a1, pre_W2, pre_b2, pre_a2, hA);
  kstats<<<256, 256, 0, stream>>>(hA, gsum, gsq);
  kfin  <<<1, 64, 0, stream>>>(gsum, gsq, bn_gamma, bn_beta, scale, shift);
  kbn   <<<256, 256, 0, stream>>>(hA, scale, shift, pooled);
  kconv <<<1024, 256, 0, stream>>>(hA, hB, nbr, conv_W,         conv_b,       act_a, pooled, 64);
  kconv <<<1024, 256, 0, stream>>>(hB, hA, nbr, conv_W + 4096,  conv_b + 64,  act_a, pooled, 128);
  kconv <<<1024, 256, 0, stream>>>(hA, hB, nbr, conv_W + 8192,  conv_b + 128, act_a, pooled, 192);
  kconv <<<1024, 256, 0, stream>>>(hB, hA, nbr, conv_W + 12288, conv_b + 192, act_a, pooled, 256);
  kffn  <<<64, 256, 0, stream>>>(pooled, ffn_W1, ffn_b1, ffn_W2, ffn_b2, out);
}

// Round 7
// 529.830 us; speedup vs baseline: 1.7347x; 1.7347x over previous
//
#include <hip/hip_runtime.h>

// Problem constants: G=64 graphs, P=1024 nodes/graph, D=64 feat, K=6 knn.
// N = 65536 nodes. fp32 in/out; KNN Gram via hi/lo-split bf16 MFMA.

typedef float4 f4;
typedef unsigned short ushort;
typedef unsigned int uint;
typedef short bf16x8 __attribute__((ext_vector_type(8)));
typedef float f32x16 __attribute__((ext_vector_type(16)));

#define FMA16(sv, wv) do { \
  a0.x += (sv).x*(wv).x; a0.y += (sv).x*(wv).y; a0.z += (sv).x*(wv).z; a0.w += (sv).x*(wv).w; \
  a1.x += (sv).y*(wv).x; a1.y += (sv).y*(wv).y; a1.z += (sv).y*(wv).z; a1.w += (sv).y*(wv).w; \
  a2.x += (sv).z*(wv).x; a2.y += (sv).z*(wv).y; a2.z += (sv).z*(wv).z; a2.w += (sv).z*(wv).w; \
  a3.x += (sv).w*(wv).x; a3.y += (sv).w*(wv).y; a3.z += (sv).w*(wv).z; a3.w += (sv).w*(wv).w; \
} while (0)

__device__ __forceinline__ ushort f2bf(float f) {
  uint u = __float_as_uint(f);
  uint r = (u + 0x7fffu + ((u >> 16) & 1u)) >> 16;   // RNE
  return (ushort)r;
}
__device__ __forceinline__ float bf2f(ushort h) { return __uint_as_float(((uint)h) << 16); }

// ---- prep: hi/lo bf16 copy of x (row of 128) + 3-term bf16 (-0.5||x||^2) --
__global__ void kprep(const float* __restrict__ x, ushort* __restrict__ xbf2,
                      uint2* __restrict__ sq3) {
  int row = blockIdx.x * 4 + (threadIdx.x >> 6);
  int lane = threadIdx.x & 63;
  float v = x[(size_t)row * 64 + lane];
  ushort hi = f2bf(v);
  ushort lo = f2bf(v - bf2f(hi));
  xbf2[(size_t)row * 128 + lane] = hi;
  xbf2[(size_t)row * 128 + 64 + lane] = lo;
  float s = v * v;
#pragma unroll
  for (int m = 32; m; m >>= 1) s += __shfl_xor(s, m, 64);
  if (lane == 0) {
    float mm = -0.5f * s;
    ushort h1 = f2bf(mm); float r1 = mm - bf2f(h1);
    ushort h2 = f2bf(r1); float r2 = r1 - bf2f(h2);
    ushort h3 = f2bf(r2);
    uint2 t; t.x = (uint)h1 | ((uint)h2 << 16); t.y = (uint)h3;
    sq3[row] = t;
  }
}

// sorted-DESC top-6 insertion (score high = near), lexicographic (s desc, idx asc)
__device__ __forceinline__ void ins6d(float s, int c, float (&D)[6], int (&I)[6]) {
  if (s > D[5] || (s == D[5] && c < I[5])) {
    D[5] = s; I[5] = c;
#pragma unroll
    for (int k = 5; k > 0; --k) {
      bool sw = (D[k] > D[k-1]) || (D[k] == D[k-1] && I[k] < I[k-1]);
      float da = sw ? D[k] : D[k-1], db = sw ? D[k-1] : D[k];
      int   ia = sw ? I[k] : I[k-1], ib = sw ? I[k-1] : I[k];
      D[k-1] = da; D[k] = db; I[k-1] = ia; I[k] = ib;
    }
  }
}

// ---- KNN via MFMA: wave owns 32 queries, loops 32 candidate chunks --------
// score = q.c - 0.5||c||^2 with hi/lo split: ch.qh + cl.qh + ch.ql (+3-term norm).
// acc col = query = lane&31, cand = (r&3)+8*(r>>2)+4*(lane>>5). Rank DESC.
__global__ __launch_bounds__(256) void kknn(const ushort* __restrict__ xbf2,
                                            const uint2* __restrict__ sq3,
                                            int* __restrict__ nbr) {
  const int tid = threadIdx.x;
  const int lane = tid & 63;
  const int w = tid >> 6;
  const int q = lane & 31;
  const int h = lane >> 5;
  const int g = blockIdx.x >> 3;               // 8 blocks (of 128 queries) per graph
  const int qglob = blockIdx.x * 128 + w * 32 + q;
  const int qloc = qglob & 1023;
  const int gbase = g << 10;

  bf16x8 Qh0, Qh1, Qh2, Qh3, Ql0, Ql1, Ql2, Ql3;
  {
    const ushort* qp = xbf2 + (size_t)qglob * 128 + 8 * h;
    Qh0 = *(const bf16x8*)(qp);       Qh1 = *(const bf16x8*)(qp + 16);
    Qh2 = *(const bf16x8*)(qp + 32);  Qh3 = *(const bf16x8*)(qp + 48);
    Ql0 = *(const bf16x8*)(qp + 64);  Ql1 = *(const bf16x8*)(qp + 80);
    Ql2 = *(const bf16x8*)(qp + 96);  Ql3 = *(const bf16x8*)(qp + 112);
  }
  bf16x8 Bsq = {0, 0, 0, 0, 0, 0, 0, 0};
  if (h == 0) { Bsq[0] = (short)0x3F80; Bsq[1] = (short)0x3F80; Bsq[2] = (short)0x3F80; }

  float Dl[6]; int Il[6];
#pragma unroll
  for (int k = 0; k < 6; ++k) { Dl[k] = -3.0e38f; Il[k] = 0x7fffffff; }

  for (int c = 0; c < 32; ++c) {
    const int cb = gbase + c * 32;
    const ushort* cp = xbf2 + (size_t)(cb + q) * 128 + 8 * h;
    bf16x8 Ah0 = *(const bf16x8*)(cp);       bf16x8 Ah1 = *(const bf16x8*)(cp + 16);
    bf16x8 Ah2 = *(const bf16x8*)(cp + 32);  bf16x8 Ah3 = *(const bf16x8*)(cp + 48);
    bf16x8 Al0 = *(const bf16x8*)(cp + 64);  bf16x8 Al1 = *(const bf16x8*)(cp + 80);
    bf16x8 Al2 = *(const bf16x8*)(cp + 96);  bf16x8 Al3 = *(const bf16x8*)(cp + 112);
    uint2 sv = sq3[cb + q];
    bf16x8 Asq = {0, 0, 0, 0, 0, 0, 0, 0};
    if (h == 0) {
      Asq[0] = (short)(sv.x & 0xffffu);
      Asq[1] = (short)(sv.x >> 16);
      Asq[2] = (short)(sv.y & 0xffffu);
    }

    f32x16 acc = {0,0,0,0,0,0,0,0,0,0,0,0,0,0,0,0};
    // hi_c . hi_q
    acc = __builtin_amdgcn_mfma_f32_32x32x16_bf16(Ah0, Qh0, acc, 0, 0, 0);
    acc = __builtin_amdgcn_mfma_f32_32x32x16_bf16(Ah1, Qh1, acc, 0, 0, 0);
    acc = __builtin_amdgcn_mfma_f32_32x32x16_bf16(Ah2, Qh2, acc, 0, 0, 0);
    acc = __builtin_amdgcn_mfma_f32_32x32x16_bf16(Ah3, Qh3, acc, 0, 0, 0);
    // lo_c . hi_q
    acc = __builtin_amdgcn_mfma_f32_32x32x16_bf16(Al0, Qh0, acc, 0, 0, 0);
    acc = __builtin_amdgcn_mfma_f32_32x32x16_bf16(Al1, Qh1, acc, 0, 0, 0);
    acc = __builtin_amdgcn_mfma_f32_32x32x16_bf16(Al2, Qh2, acc, 0, 0, 0);
    acc = __builtin_amdgcn_mfma_f32_32x32x16_bf16(Al3, Qh3, acc, 0, 0, 0);
    // hi_c . lo_q
    acc = __builtin_amdgcn_mfma_f32_32x32x16_bf16(Ah0, Ql0, acc, 0, 0, 0);
    acc = __builtin_amdgcn_mfma_f32_32x32x16_bf16(Ah1, Ql1, acc, 0, 0, 0);
    acc = __builtin_amdgcn_mfma_f32_32x32x16_bf16(Ah2, Ql2, acc, 0, 0, 0);
    acc = __builtin_amdgcn_mfma_f32_32x32x16_bf16(Ah3, Ql3, acc, 0, 0, 0);
    // -0.5||c||^2 (3-term bf16, error ~4e-7)
    acc = __builtin_amdgcn_mfma_f32_32x32x16_bf16(Asq, Bsq, acc, 0, 0, 0);

    const int cl0 = c * 32 + 4 * h;
#pragma unroll
    for (int r = 0; r < 16; ++r) {
      const int candl = cl0 + (r & 3) + 8 * (r >> 2);
      const float s = acc[r];
      if (candl != qloc) ins6d(s, candl, Dl, Il);
    }
  }

  // merge the two half-wave candidate sets: SNAPSHOT partner's list first
  float ds[6]; int is[6];
#pragma unroll
  for (int k = 0; k < 6; ++k) {
    ds[k] = __shfl_xor(Dl[k], 32, 64);
    is[k] = __shfl_xor(Il[k], 32, 64);
  }
#pragma unroll
  for (int k = 0; k < 6; ++k) ins6d(ds[k], is[k], Dl, Il);

  if (h == 0) {
    const int ob = qglob * 6;
#pragma unroll
    for (int k = 0; k < 6; ++k) nbr[ob + k] = gbase + Il[k];
  }
}

// ---------------- pre_nn: two fused 64x64 GEMMs + PReLU, 64 rows per block --
__global__ __launch_bounds__(256) void kpre(const float* __restrict__ x,
    const float* __restrict__ W1, const float* __restrict__ b1, const float* __restrict__ p1,
    const float* __restrict__ W2, const float* __restrict__ b2, const float* __restrict__ p2,
    float* __restrict__ hpre) {
  __shared__ float xT[64][68];
  __shared__ float yT[64][68];
  __shared__ float W1l[64][64];
  __shared__ float W2l[64][64];
  __shared__ float bb1[64], aa1[64], bb2[64], aa2[64];
  const int tid = threadIdx.x;
  const int base = blockIdx.x * 64;
#pragma unroll
  for (int k = 0; k < 16; ++k) {
    int idx = tid + 256 * k;
    W1l[idx >> 6][idx & 63] = W1[idx];
    W2l[idx >> 6][idx & 63] = W2[idx];
  }
  if (tid < 64) { bb1[tid] = b1[tid]; aa1[tid] = p1[tid]; bb2[tid] = b2[tid]; aa2[tid] = p2[tid]; }
  const int il = tid >> 2, qq = tid & 3;
  {
    const f4* src = (const f4*)(x + (size_t)(base + il) * 64) + qq * 4;
#pragma unroll
    for (int m = 0; m < 4; ++m) {
      f4 v = src[m];
      int d0 = qq * 16 + m * 4;
      xT[d0+0][il] = v.x; xT[d0+1][il] = v.y; xT[d0+2][il] = v.z; xT[d0+3][il] = v.w;
    }
  }
  __syncthreads();
  const int ti = tid & 15, to = tid >> 4;
  f4 a0 = {0.f,0.f,0.f,0.f}, a1 = a0, a2 = a0, a3 = a0;
#pragma unroll 16
  for (int d = 0; d < 64; ++d) {
    f4 sv = *(const f4*)&xT[d][4*ti];
    f4 wv = *(const f4*)&W1l[d][4*to];
    FMA16(sv, wv);
  }
#define EPI1(AR, r) { \
    const int row = 4*ti + (r); float v; \
    v = AR.x + bb1[4*to+0]; v = v >= 0.f ? v : aa1[4*to+0]*v; yT[4*to+0][row] = v; \
    v = AR.y + bb1[4*to+1]; v = v >= 0.f ? v : aa1[4*to+1]*v; yT[4*to+1][row] = v; \
    v = AR.z + bb1[4*to+2]; v = v >= 0.f ? v : aa1[4*to+2]*v; yT[4*to+2][row] = v; \
    v = AR.w + bb1[4*to+3]; v = v >= 0.f ? v : aa1[4*to+3]*v; yT[4*to+3][row] = v; }
  EPI1(a0, 0) EPI1(a1, 1) EPI1(a2, 2) EPI1(a3, 3)
#undef EPI1
  __syncthreads();
  a0.x=a0.y=a0.z=a0.w=0.f; a1=a0; a2=a0; a3=a0;
#pragma unroll 16
  for (int d = 0; d < 64; ++d) {
    f4 sv = *(const f4*)&yT[d][4*ti];
    f4 wv = *(const f4*)&W2l[d][4*to];
    FMA16(sv, wv);
  }
#define EPI2(AR, r) { \
    const int i = base + 4*ti + (r); f4 ov; float v; \
    v = AR.x + bb2[4*to+0]; ov.x = v >= 0.f ? v : aa2[4*to+0]*v; \
    v = AR.y + bb2[4*to+1]; ov.y = v >= 0.f ? v : aa2[4*to+1]*v; \
    v = AR.z + bb2[4*to+2]; ov.z = v >= 0.f ? v : aa2[4*to+2]*v; \
    v = AR.w + bb2[4*to+3]; ov.w = v >= 0.f ? v : aa2[4*to+3]*v; \
    *((f4*)(hpre + (size_t)i * 64) + to) = ov; }
  EPI2(a0, 0) EPI2(a1, 1) EPI2(a2, 2) EPI2(a3, 3)
#undef EPI2
}

// ---------------- BN stats: per-feature sum / sumsq ------------------------
__global__ void kstats(const float* __restrict__ h, float* __restrict__ gsum,
                       float* __restrict__ gsq) {
  __shared__ float r1[256], r2[256];
  const int tid = threadIdx.x;
  const int f = tid & 63, sub = tid >> 6;
  const size_t rbase = (size_t)blockIdx.x * 256 + sub;
  float s = 0.f, s2 = 0.f;
  for (int k = 0; k < 64; ++k) {
    float v = h[(rbase + 4 * k) * 64 + f];
    s += v; s2 += v * v;
  }
  r1[tid] = s; r2[tid] = s2;
  __syncthreads();
  if (tid < 64) {
    s  = r1[tid] + r1[tid+64] + r1[tid+128] + r1[tid+192];
    s2 = r2[tid] + r2[tid+64] + r2[tid+128] + r2[tid+192];
    atomicAdd(&gsum[tid], s);
    atomicAdd(&gsq[tid], s2);
  }
}

__global__ void kfin(const float* __restrict__ gsum, const float* __restrict__ gsq,
                     const float* __restrict__ gamma, const float* __restrict__ beta,
                     float* __restrict__ scale, float* __restrict__ shift) {
  int f = threadIdx.x;
  float mu = gsum[f] * (1.f / 65536.f);
  float var = gsq[f] * (1.f / 65536.f) - mu * mu;
  float sc = gamma[f] * rsqrtf(var + 1e-5f);
  scale[f] = sc;
  shift[f] = beta[f] - mu * sc;
}

// ---------------- apply BN in place + pool stage 0 -------------------------
__global__ void kbn(float* __restrict__ h, const float* __restrict__ scale,
                    const float* __restrict__ shift, float* __restrict__ pooled) {
  __shared__ float red[256];
  const int tid = threadIdx.x;
  const int f = tid & 63, sub = tid >> 6;
  const size_t rbase = (size_t)blockIdx.x * 256 + sub;
  const int g = blockIdx.x >> 2;
  const float sc = scale[f], sh = shift[f];
  float acc = 0.f;
  for (int k = 0; k < 64; ++k) {
    size_t off = (rbase + 4 * k) * 64 + f;
    float v = h[off] * sc + sh;
    h[off] = v;
    acc += v;
  }
  red[tid] = acc;
  __syncthreads();
  if (tid < 64) {
    float t = red[tid] + red[tid+64] + red[tid+128] + red[tid+192];
    atomicAdd(&pooled[g * 320 + tid], t);
  }
}

// ---------------- one conv layer: gather-sum + GEMM + PReLU + pool ---------
__global__ __launch_bounds__(256) void kconv(const float* __restrict__ hIn,
    float* __restrict__ hOut, const int* __restrict__ nbr,
    const float* __restrict__ W, const float* __restrict__ bias,
    const float* __restrict__ act, float* __restrict__ pooled, int stageoff) {
  __shared__ float sT[64][68];
  __shared__ float Wl[64][64];
  __shared__ float bb[64], aa[64], pool[64];
  const int tid = threadIdx.x;
  const int base = blockIdx.x * 64;
  const int g = base >> 10;
#pragma unroll
  for (int k = 0; k < 16; ++k) { int idx = tid + 256 * k; Wl[idx >> 6][idx & 63] = W[idx]; }
  if (tid < 64) { bb[tid] = bias[tid]; aa[tid] = act[tid]; pool[tid] = 0.f; }

  const int il = tid >> 2, qq = tid & 3;
  {
    f4 acc0 = {0.f,0.f,0.f,0.f}, acc1 = acc0, acc2 = acc0, acc3 = acc0;
    const int i = base + il;
#pragma unroll
    for (int k = 0; k < 6; ++k) {
      int j = nbr[i * 6 + k];
      const f4* hj = (const f4*)(hIn + (size_t)j * 64) + qq * 4;
      f4 v0 = hj[0], v1 = hj[1], v2 = hj[2], v3 = hj[3];
      acc0.x += v0.x; acc0.y += v0.y; acc0.z += v0.z; acc0.w += v0.w;
      acc1.x += v1.x; acc1.y += v1.y; acc1.z += v1.z; acc1.w += v1.w;
      acc2.x += v2.x; acc2.y += v2.y; acc2.z += v2.z; acc2.w += v2.w;
      acc3.x += v3.x; acc3.y += v3.y; acc3.z += v3.z; acc3.w += v3.w;
    }
    const int d0 = qq * 16;
    sT[d0+ 0][il]=acc0.x; sT[d0+ 1][il]=acc0.y; sT[d0+ 2][il]=acc0.z; sT[d0+ 3][il]=acc0.w;
    sT[d0+ 4][il]=acc1.x; sT[d0+ 5][il]=acc1.y; sT[d0+ 6][il]=acc1.z; sT[d0+ 7][il]=acc1.w;
    sT[d0+ 8][il]=acc2.x; sT[d0+ 9][il]=acc2.y; sT[d0+10][il]=acc2.z; sT[d0+11][il]=acc2.w;
    sT[d0+12][il]=acc3.x; sT[d0+13][il]=acc3.y; sT[d0+14][il]=acc3.z; sT[d0+15][il]=acc3.w;
  }
  __syncthreads();

  const int ti = tid & 15, to = tid >> 4;
  f4 a0 = {0.f,0.f,0.f,0.f}, a1 = a0, a2 = a0, a3 = a0;
#pragma unroll 16
  for (int d = 0; d < 64; ++d) {
    f4 sv = *(const f4*)&sT[d][4*ti];
    f4 wv = *(const f4*)&Wl[d][4*to];
    FMA16(sv, wv);
  }

  const float bs0 = 6.f*bb[4*to+0], bs1 = 6.f*bb[4*to+1], bs2 = 6.f*bb[4*to+2], bs3 = 6.f*bb[4*to+3];
  const float av0 = aa[4*to+0], av1 = aa[4*to+1], av2 = aa[4*to+2], av3 = aa[4*to+3];
  float p0 = 0.f, pp1 = 0.f, pp2 = 0.f, pp3 = 0.f;
#define CEPI(AR, r) { \
    const int i = base + 4*ti + (r); \
    f4 res = *((const f4*)(hIn + (size_t)i * 64) + to); \
    f4 ov; float v; \
    v = AR.x + bs0 + res.x; v = v >= 0.f ? v : av0 * v; ov.x = v; p0  += v; \
    v = AR.y + bs1 + res.y; v = v >= 0.f ? v : av1 * v; ov.y = v; pp1 += v; \
    v = AR.z + bs2 + res.z; v = v >= 0.f ? v : av2 * v; ov.z = v; pp2 += v; \
    v = AR.w + bs3 + res.w; v = v >= 0.f ? v : av3 * v; ov.w = v; pp3 += v; \
    *((f4*)(hOut + (size_t)i * 64) + to) = ov; }
  CEPI(a0, 0) CEPI(a1, 1) CEPI(a2, 2) CEPI(a3, 3)
#undef CEPI
  atomicAdd(&pool[4*to+0], p0);
  atomicAdd(&pool[4*to+1], pp1);
  atomicAdd(&pool[4*to+2], pp2);
  atomicAdd(&pool[4*to+3], pp3);
  __syncthreads();
  if (tid < 64) atomicAdd(&pooled[g * 320 + stageoff + tid], pool[tid]);
}

// ---------------- FFN head: one block per graph ----------------------------
__global__ __launch_bounds__(256) void kffn(const float* __restrict__ pooled,
    const float* __restrict__ W1, const float* __restrict__ b1,
    const float* __restrict__ W2, const float* __restrict__ b2,
    float* __restrict__ out) {
  __shared__ float pg[320];
  __shared__ float z1[320];
  __shared__ float red[4];
  const int g = blockIdx.x, tid = threadIdx.x;
  for (int i = tid; i < 320; i += 256) pg[i] = pooled[g * 320 + i];
  __syncthreads();
  for (int o = tid; o < 320; o += 256) {
    float acc = b1[o];
    for (int d = 0; d < 320; ++d) acc += pg[d] * W1[d * 320 + o];
    z1[o] = acc >= 0.f ? acc : 0.01f * acc;
  }
  __syncthreads();
  float p = 0.f;
  for (int o = tid; o < 320; o += 256) p += z1[o] * W2[o];
#pragma unroll
  for (int m = 32; m; m >>= 1) p += __shfl_xor(p, m, 64);
  if ((tid & 63) == 0) red[tid >> 6] = p;
  __syncthreads();
  if (tid == 0) out[g] = red[0] + red[1] + red[2] + red[3] + b2[0];
}

extern "C" void kernel_launch(void* const* d_in, const int* in_sizes, int n_in,
                              void* d_out, int out_size, void* d_ws, size_t ws_size,
                              hipStream_t stream) {
  const float* x        = (const float*)d_in[0];
  const float* pre_W1   = (const float*)d_in[2];
  const float* pre_b1   = (const float*)d_in[3];
  const float* pre_a1   = (const float*)d_in[4];
  const float* pre_W2   = (const float*)d_in[5];
  const float* pre_b2   = (const float*)d_in[6];
  const float* pre_a2   = (const float*)d_in[7];
  const float* bn_gamma = (const float*)d_in[8];
  const float* bn_beta  = (const float*)d_in[9];
  const float* act_a    = (const float*)d_in[10];
  const float* conv_W   = (const float*)d_in[11];
  const float* conv_b   = (const float*)d_in[12];
  const float* ffn_W1   = (const float*)d_in[13];
  const float* ffn_b1   = (const float*)d_in[14];
  const float* ffn_W2   = (const float*)d_in[15];
  const float* ffn_b2   = (const float*)d_in[16];
  float* out = (float*)d_out;

  float* ws = (float*)d_ws;
  float* hA = ws;                                   // N*64 floats (16 MB)
  float* hB = ws + 4194304;                         // N*64 floats (16 MB)
  // Aliases (stream-ordered, so no hazard):
  //   xbf2 = hB region (16 MiB exactly): dead before kconv1 first writes hB.
  //   sq3  = head of hA (512 KB): dead before kpre writes hA.
  ushort* xbf2 = (ushort*)hB;                       // N*128 bf16 hi/lo
  uint2*  sq3  = (uint2*)hA;                        // N uint2
  int*   nbr   = (int*)(ws + 8388608);              // N*6 ints
  float* stats = ws + 8388608 + 393216;
  float* gsum  = stats;
  float* gsq   = stats + 64;
  float* scale = stats + 128;
  float* shift = stats + 192;
  float* pooled = stats + 256;                      // 64*320 floats

  hipMemsetAsync(stats, 0, (256 + 64 * 320) * sizeof(float), stream);

  kprep <<<16384, 256, 0, stream>>>(x, xbf2, sq3);
  kknn  <<<512, 256, 0, stream>>>(xbf2, sq3, nbr);
  kpre  <<<1024, 256, 0, stream>>>(x, pre_W1, pre_b1, pre_a1, pre_W2, pre_b2, pre_a2, hA);
  kstats<<<256, 256, 0, stream>>>(hA, gsum, gsq);
  kfin  <<<1, 64, 0, stream>>>(gsum, gsq, bn_gamma, bn_beta, scale, shift);
  kbn   <<<256, 256, 0, stream>>>(hA, scale, shift, pooled);
  kconv <<<1024, 256, 0, stream>>>(hA, hB, nbr, conv_W,         conv_b,       act_a, pooled, 64);
  kconv <<<1024, 256, 0, stream>>>(hB, hA, nbr, conv_W + 4096,  conv_b + 64,  act_a, pooled, 128);
  kconv <<<1024, 256, 0, stream>>>(hA, hB, nbr, conv_W + 8192,  conv_b + 128, act_a, pooled, 192);
  kconv <<<1024, 256, 0, stream>>>(hB, hA, nbr, conv_W + 12288, conv_b + 192, act_a, pooled, 256);
  kffn  <<<64, 256, 0, stream>>>(pooled, ffn_W1, ffn_b1, ffn_W2, ffn_b2, out);
}

// Round 8
// 339.190 us; speedup vs baseline: 2.7096x; 1.5620x over previous
//
#include <hip/hip_runtime.h>

// G=64 graphs, P=1024 nodes/graph, D=64 feat, K=6 knn. N=65536.
// fp32 in/out; KNN Gram via hi/lo-split bf16 MFMA + packed-key cascade top-6.

typedef float4 f4;
typedef unsigned short ushort;
typedef unsigned int uint;
typedef short bf16x8 __attribute__((ext_vector_type(8)));
typedef float f32x16 __attribute__((ext_vector_type(16)));

#define FMA16(sv, wv) do { \
  a0.x += (sv).x*(wv).x; a0.y += (sv).x*(wv).y; a0.z += (sv).x*(wv).z; a0.w += (sv).x*(wv).w; \
  a1.x += (sv).y*(wv).x; a1.y += (sv).y*(wv).y; a1.z += (sv).y*(wv).z; a1.w += (sv).y*(wv).w; \
  a2.x += (sv).z*(wv).x; a2.y += (sv).z*(wv).y; a2.z += (sv).z*(wv).z; a2.w += (sv).z*(wv).w; \
  a3.x += (sv).w*(wv).x; a3.y += (sv).w*(wv).y; a3.z += (sv).w*(wv).z; a3.w += (sv).w*(wv).w; \
} while (0)

__device__ __forceinline__ ushort f2bf(float f) {
  uint u = __float_as_uint(f);
  uint r = (u + 0x7fffu + ((u >> 16) & 1u)) >> 16;   // RNE
  return (ushort)r;
}
__device__ __forceinline__ float bf2f(ushort h) { return __uint_as_float(((uint)h) << 16); }

// 12-op branch-free top-6 cascade on sortable packed keys (desc)
__device__ __forceinline__ void cas6(uint x, uint& m0, uint& m1, uint& m2,
                                     uint& m3, uint& m4, uint& m5) {
  uint t;
  t = min(m0, x); m0 = max(m0, x); x = t;
  t = min(m1, x); m1 = max(m1, x); x = t;
  t = min(m2, x); m2 = max(m2, x); x = t;
  t = min(m3, x); m3 = max(m3, x); x = t;
  t = min(m4, x); m4 = max(m4, x); x = t;
  m5 = max(m5, x);
}

// ---- prep: hi/lo bf16 copy of x (row of 128) + 3-term bf16 (-0.5||x||^2) --
__global__ void kprep(const float* __restrict__ x, ushort* __restrict__ xbf2,
                      uint2* __restrict__ sq3) {
  int row = blockIdx.x * 4 + (threadIdx.x >> 6);
  int lane = threadIdx.x & 63;
  float v = x[(size_t)row * 64 + lane];
  ushort hi = f2bf(v);
  ushort lo = f2bf(v - bf2f(hi));
  xbf2[(size_t)row * 128 + lane] = hi;
  xbf2[(size_t)row * 128 + 64 + lane] = lo;
  float s = v * v;
#pragma unroll
  for (int m = 32; m; m >>= 1) s += __shfl_xor(s, m, 64);
  if (lane == 0) {
    float mm = -0.5f * s;
    ushort h1 = f2bf(mm); float r1 = mm - bf2f(h1);
    ushort h2 = f2bf(r1); float r2 = r1 - bf2f(h2);
    ushort h3 = f2bf(r2);
    uint2 t; t.x = (uint)h1 | ((uint)h2 << 16); t.y = (uint)h3;
    sq3[row] = t;
  }
}

// ---- KNN: block = 32 queries; 4 waves each scan 8 chunks of 32 candidates.
// score = q.c - 0.5||c||^2; packed key = 22b fixed-point score | 10b (1023-idx).
__global__ __launch_bounds__(256, 4) void kknn(const ushort* __restrict__ xbf2,
                                               const uint2* __restrict__ sq3,
                                               int* __restrict__ nbr) {
  __shared__ uint skey[4][32][6];
  const int tid = threadIdx.x;
  const int lane = tid & 63;
  const int w = tid >> 6;
  const int q = lane & 31;
  const int h = lane >> 5;
  const int g = blockIdx.x >> 5;
  const int qtile = blockIdx.x & 31;
  const int gbase = g << 10;
  const int qloc = qtile * 32 + q;
  const int qglob = gbase + qloc;

  bf16x8 Qh0, Qh1, Qh2, Qh3, Ql0, Ql1, Ql2, Ql3;
  {
    const ushort* qp = xbf2 + (size_t)qglob * 128 + 8 * h;
    Qh0 = *(const bf16x8*)(qp);       Qh1 = *(const bf16x8*)(qp + 16);
    Qh2 = *(const bf16x8*)(qp + 32);  Qh3 = *(const bf16x8*)(qp + 48);
    Ql0 = *(const bf16x8*)(qp + 64);  Ql1 = *(const bf16x8*)(qp + 80);
    Ql2 = *(const bf16x8*)(qp + 96);  Ql3 = *(const bf16x8*)(qp + 112);
  }
  bf16x8 Bsq = {0, 0, 0, 0, 0, 0, 0, 0};
  if (h == 0) { Bsq[0] = (short)0x3F80; Bsq[1] = (short)0x3F80; Bsq[2] = (short)0x3F80; }

  uint m0 = 0, m1 = 0, m2 = 0, m3 = 0, m4 = 0, m5 = 0;

  for (int cc = 0; cc < 8; ++cc) {
    const int cg = w * 8 + cc;                 // global chunk idx 0..31
    const int cb = gbase + cg * 32;
    const ushort* cp = xbf2 + (size_t)(cb + q) * 128 + 8 * h;
    bf16x8 Ah0 = *(const bf16x8*)(cp);       bf16x8 Ah1 = *(const bf16x8*)(cp + 16);
    bf16x8 Ah2 = *(const bf16x8*)(cp + 32);  bf16x8 Ah3 = *(const bf16x8*)(cp + 48);
    bf16x8 Al0 = *(const bf16x8*)(cp + 64);  bf16x8 Al1 = *(const bf16x8*)(cp + 80);
    bf16x8 Al2 = *(const bf16x8*)(cp + 96);  bf16x8 Al3 = *(const bf16x8*)(cp + 112);
    uint2 sv = sq3[cb + q];
    bf16x8 Asq = {0, 0, 0, 0, 0, 0, 0, 0};
    if (h == 0) {
      Asq[0] = (short)(sv.x & 0xffffu);
      Asq[1] = (short)(sv.x >> 16);
      Asq[2] = (short)(sv.y & 0xffffu);
    }

    f32x16 acc = {0,0,0,0,0,0,0,0,0,0,0,0,0,0,0,0};
    acc = __builtin_amdgcn_mfma_f32_32x32x16_bf16(Ah0, Qh0, acc, 0, 0, 0);
    acc = __builtin_amdgcn_mfma_f32_32x32x16_bf16(Ah1, Qh1, acc, 0, 0, 0);
    acc = __builtin_amdgcn_mfma_f32_32x32x16_bf16(Ah2, Qh2, acc, 0, 0, 0);
    acc = __builtin_amdgcn_mfma_f32_32x32x16_bf16(Ah3, Qh3, acc, 0, 0, 0);
    acc = __builtin_amdgcn_mfma_f32_32x32x16_bf16(Al0, Qh0, acc, 0, 0, 0);
    acc = __builtin_amdgcn_mfma_f32_32x32x16_bf16(Al1, Qh1, acc, 0, 0, 0);
    acc = __builtin_amdgcn_mfma_f32_32x32x16_bf16(Al2, Qh2, acc, 0, 0, 0);
    acc = __builtin_amdgcn_mfma_f32_32x32x16_bf16(Al3, Qh3, acc, 0, 0, 0);
    acc = __builtin_amdgcn_mfma_f32_32x32x16_bf16(Ah0, Ql0, acc, 0, 0, 0);
    acc = __builtin_amdgcn_mfma_f32_32x32x16_bf16(Ah1, Ql1, acc, 0, 0, 0);
    acc = __builtin_amdgcn_mfma_f32_32x32x16_bf16(Ah2, Ql2, acc, 0, 0, 0);
    acc = __builtin_amdgcn_mfma_f32_32x32x16_bf16(Ah3, Ql3, acc, 0, 0, 0);
    acc = __builtin_amdgcn_mfma_f32_32x32x16_bf16(Asq, Bsq, acc, 0, 0, 0);

    const int cl0 = cg * 32 + 4 * h;
    if (cg == qtile) {                         // diagonal chunk: mask self
#pragma unroll
      for (int r = 0; r < 16; ++r) {
        const int candl = cl0 + (r & 3) + 8 * (r >> 2);
        uint u = __float_as_uint(acc[r] + 1536.0f);
        uint key = ((u << 9) & 0xFFFFFC00u) | (uint)(1023 - candl);
        if (candl == qloc) key = 0u;
        cas6(key, m0, m1, m2, m3, m4, m5);
      }
    } else {
#pragma unroll
      for (int r = 0; r < 16; ++r) {
        const int candl = cl0 + (r & 3) + 8 * (r >> 2);
        uint u = __float_as_uint(acc[r] + 1536.0f);
        uint key = ((u << 9) & 0xFFFFFC00u) | (uint)(1023 - candl);
        cas6(key, m0, m1, m2, m3, m4, m5);
      }
    }
  }

  // merge the two half-wave lists (snapshot partner first, then insert)
  {
    uint p0 = (uint)__shfl_xor((int)m0, 32, 64);
    uint p1 = (uint)__shfl_xor((int)m1, 32, 64);
    uint p2 = (uint)__shfl_xor((int)m2, 32, 64);
    uint p3 = (uint)__shfl_xor((int)m3, 32, 64);
    uint p4 = (uint)__shfl_xor((int)m4, 32, 64);
    uint p5 = (uint)__shfl_xor((int)m5, 32, 64);
    cas6(p0, m0, m1, m2, m3, m4, m5);
    cas6(p1, m0, m1, m2, m3, m4, m5);
    cas6(p2, m0, m1, m2, m3, m4, m5);
    cas6(p3, m0, m1, m2, m3, m4, m5);
    cas6(p4, m0, m1, m2, m3, m4, m5);
    cas6(p5, m0, m1, m2, m3, m4, m5);
  }
  if (h == 0) {
    skey[w][q][0] = m0; skey[w][q][1] = m1; skey[w][q][2] = m2;
    skey[w][q][3] = m3; skey[w][q][4] = m4; skey[w][q][5] = m5;
  }
  __syncthreads();

  if (tid < 32) {
    uint f0 = skey[0][tid][0], f1 = skey[0][tid][1], f2 = skey[0][tid][2];
    uint f3 = skey[0][tid][3], f4v = skey[0][tid][4], f5 = skey[0][tid][5];
#pragma unroll
    for (int ww = 1; ww < 4; ++ww)
#pragma unroll
      for (int k = 0; k < 6; ++k)
        cas6(skey[ww][tid][k], f0, f1, f2, f3, f4v, f5);
    const int ob = (gbase + qtile * 32 + tid) * 6;
    nbr[ob + 0] = gbase + 1023 - (int)(f0 & 1023u);
    nbr[ob + 1] = gbase + 1023 - (int)(f1 & 1023u);
    nbr[ob + 2] = gbase + 1023 - (int)(f2 & 1023u);
    nbr[ob + 3] = gbase + 1023 - (int)(f3 & 1023u);
    nbr[ob + 4] = gbase + 1023 - (int)(f4v & 1023u);
    nbr[ob + 5] = gbase + 1023 - (int)(f5 & 1023u);
  }
}

// ---- pre_nn: two fused 64x64 GEMMs + PReLU + per-graph/global stats -------
__global__ __launch_bounds__(256) void kpre(const float* __restrict__ x,
    const float* __restrict__ W1, const float* __restrict__ b1, const float* __restrict__ p1,
    const float* __restrict__ W2, const float* __restrict__ b2, const float* __restrict__ p2,
    float* __restrict__ hpre, float* __restrict__ gsumg, float* __restrict__ gsq) {
  __shared__ float xT[64][68];
  __shared__ float yT[64][68];
  __shared__ float W1l[64][64];
  __shared__ float W2l[64][64];
  __shared__ float bb1[64], aa1[64], bb2[64], aa2[64];
  __shared__ float ls[64], lq[64];
  const int tid = threadIdx.x;
  const int base = blockIdx.x * 64;
  const int g = base >> 10;
#pragma unroll
  for (int k = 0; k < 16; ++k) {
    int idx = tid + 256 * k;
    W1l[idx >> 6][idx & 63] = W1[idx];
    W2l[idx >> 6][idx & 63] = W2[idx];
  }
  if (tid < 64) {
    bb1[tid] = b1[tid]; aa1[tid] = p1[tid]; bb2[tid] = b2[tid]; aa2[tid] = p2[tid];
    ls[tid] = 0.f; lq[tid] = 0.f;
  }
  const int il = tid >> 2, qq = tid & 3;
  {
    const f4* src = (const f4*)(x + (size_t)(base + il) * 64) + qq * 4;
#pragma unroll
    for (int m = 0; m < 4; ++m) {
      f4 v = src[m];
      int d0 = qq * 16 + m * 4;
      xT[d0+0][il] = v.x; xT[d0+1][il] = v.y; xT[d0+2][il] = v.z; xT[d0+3][il] = v.w;
    }
  }
  __syncthreads();
  const int ti = tid & 15, to = tid >> 4;
  f4 a0 = {0.f,0.f,0.f,0.f}, a1 = a0, a2 = a0, a3 = a0;
#pragma unroll 16
  for (int d = 0; d < 64; ++d) {
    f4 sv = *(const f4*)&xT[d][4*ti];
    f4 wv = *(const f4*)&W1l[d][4*to];
    FMA16(sv, wv);
  }
#define EPI1(AR, r) { \
    const int row = 4*ti + (r); float v; \
    v = AR.x + bb1[4*to+0]; v = v >= 0.f ? v : aa1[4*to+0]*v; yT[4*to+0][row] = v; \
    v = AR.y + bb1[4*to+1]; v = v >= 0.f ? v : aa1[4*to+1]*v; yT[4*to+1][row] = v; \
    v = AR.z + bb1[4*to+2]; v = v >= 0.f ? v : aa1[4*to+2]*v; yT[4*to+2][row] = v; \
    v = AR.w + bb1[4*to+3]; v = v >= 0.f ? v : aa1[4*to+3]*v; yT[4*to+3][row] = v; }
  EPI1(a0, 0) EPI1(a1, 1) EPI1(a2, 2) EPI1(a3, 3)
#undef EPI1
  __syncthreads();
  a0.x=a0.y=a0.z=a0.w=0.f; a1=a0; a2=a0; a3=a0;
#pragma unroll 16
  for (int d = 0; d < 64; ++d) {
    f4 sv = *(const f4*)&yT[d][4*ti];
    f4 wv = *(const f4*)&W2l[d][4*to];
    FMA16(sv, wv);
  }
  float fs0=0.f,fs1=0.f,fs2=0.f,fs3=0.f, fq0=0.f,fq1=0.f,fq2=0.f,fq3=0.f;
#define EPI2(AR, r) { \
    const int i = base + 4*ti + (r); f4 ov; float v; \
    v = AR.x + bb2[4*to+0]; ov.x = v >= 0.f ? v : aa2[4*to+0]*v; \
    v = AR.y + bb2[4*to+1]; ov.y = v >= 0.f ? v : aa2[4*to+1]*v; \
    v = AR.z + bb2[4*to+2]; ov.z = v >= 0.f ? v : aa2[4*to+2]*v; \
    v = AR.w + bb2[4*to+3]; ov.w = v >= 0.f ? v : aa2[4*to+3]*v; \
    fs0 += ov.x; fq0 += ov.x*ov.x; fs1 += ov.y; fq1 += ov.y*ov.y; \
    fs2 += ov.z; fq2 += ov.z*ov.z; fs3 += ov.w; fq3 += ov.w*ov.w; \
    *((f4*)(hpre + (size_t)i * 64) + to) = ov; }
  EPI2(a0, 0) EPI2(a1, 1) EPI2(a2, 2) EPI2(a3, 3)
#undef EPI2
  atomicAdd(&ls[4*to+0], fs0); atomicAdd(&lq[4*to+0], fq0);
  atomicAdd(&ls[4*to+1], fs1); atomicAdd(&lq[4*to+1], fq1);
  atomicAdd(&ls[4*to+2], fs2); atomicAdd(&lq[4*to+2], fq2);
  atomicAdd(&ls[4*to+3], fs3); atomicAdd(&lq[4*to+3], fq3);
  __syncthreads();
  if (tid < 64) {
    atomicAdd(&gsumg[g * 64 + tid], ls[tid]);
    atomicAdd(&gsq[tid], lq[tid]);
  }
}

// ---- finalize BN: scale/shift + analytic stage-0 pool ---------------------
__global__ void kfin(const float* __restrict__ gsumg, const float* __restrict__ gsq,
                     const float* __restrict__ gamma, const float* __restrict__ beta,
                     float* __restrict__ scale, float* __restrict__ shift,
                     float* __restrict__ pooled) {
  const int g = blockIdx.x, f = threadIdx.x;
  float s = 0.f;
  for (int g2 = 0; g2 < 64; ++g2) s += gsumg[g2 * 64 + f];
  float mu = s * (1.f / 65536.f);
  float var = gsq[f] * (1.f / 65536.f) - mu * mu;
  float sc = gamma[f] * rsqrtf(var + 1e-5f);
  float sh = beta[f] - mu * sc;
  pooled[g * 320 + f] = sc * gsumg[g * 64 + f] + 1024.f * sh;
  if (g == 0) { scale[f] = sc; shift[f] = sh; }
}

// ---- conv layer: gather-sum (+inline BN on layer 1) + GEMM + PReLU + pool -
template <int BN>
__global__ __launch_bounds__(256) void kconv(const float* __restrict__ hIn,
    float* __restrict__ hOut, const int* __restrict__ nbr,
    const float* __restrict__ W, const float* __restrict__ bias,
    const float* __restrict__ act, const float* __restrict__ scale,
    const float* __restrict__ shift, float* __restrict__ pooled, int stageoff) {
  __shared__ float sT[64][68];
  __shared__ float Wl[64][64];
  __shared__ float bb[64], aa[64], pool[64];
  __shared__ float scl[64], shl[64];
  const int tid = threadIdx.x;
  const int base = blockIdx.x * 64;
  const int g = base >> 10;
#pragma unroll
  for (int k = 0; k < 16; ++k) { int idx = tid + 256 * k; Wl[idx >> 6][idx & 63] = W[idx]; }
  if (tid < 64) {
    bb[tid] = bias[tid]; aa[tid] = act[tid]; pool[tid] = 0.f;
    if (BN) { scl[tid] = scale[tid]; shl[tid] = shift[tid]; }
  }

  const int il = tid >> 2, qq = tid & 3;
  {
    f4 acc0 = {0.f,0.f,0.f,0.f}, acc1 = acc0, acc2 = acc0, acc3 = acc0;
    const int i = base + il;
#pragma unroll
    for (int k = 0; k < 6; ++k) {
      int j = nbr[i * 6 + k];
      const f4* hj = (const f4*)(hIn + (size_t)j * 64) + qq * 4;
      f4 v0 = hj[0], v1 = hj[1], v2 = hj[2], v3 = hj[3];
      acc0.x += v0.x; acc0.y += v0.y; acc0.z += v0.z; acc0.w += v0.w;
      acc1.x += v1.x; acc1.y += v1.y; acc1.z += v1.z; acc1.w += v1.w;
      acc2.x += v2.x; acc2.y += v2.y; acc2.z += v2.z; acc2.w += v2.w;
      acc3.x += v3.x; acc3.y += v3.y; acc3.z += v3.z; acc3.w += v3.w;
    }
    const int d0 = qq * 16;
    if (BN) {
      // LDS barrier below guards scl/shl first-use ordering? No: scl written by
      // tid<64 before any sync; gather threads use it here -> need the values.
      // They were written in this same pre-sync region by other threads, so
      // synchronize first via a lightweight path: defer BN to post-sync instead.
      sT[d0+ 0][il]=acc0.x; sT[d0+ 1][il]=acc0.y; sT[d0+ 2][il]=acc0.z; sT[d0+ 3][il]=acc0.w;
      sT[d0+ 4][il]=acc1.x; sT[d0+ 5][il]=acc1.y; sT[d0+ 6][il]=acc1.z; sT[d0+ 7][il]=acc1.w;
      sT[d0+ 8][il]=acc2.x; sT[d0+ 9][il]=acc2.y; sT[d0+10][il]=acc2.z; sT[d0+11][il]=acc2.w;
      sT[d0+12][il]=acc3.x; sT[d0+13][il]=acc3.y; sT[d0+14][il]=acc3.z; sT[d0+15][il]=acc3.w;
    } else {
      sT[d0+ 0][il]=acc0.x; sT[d0+ 1][il]=acc0.y; sT[d0+ 2][il]=acc0.z; sT[d0+ 3][il]=acc0.w;
      sT[d0+ 4][il]=acc1.x; sT[d0+ 5][il]=acc1.y; sT[d0+ 6][il]=acc1.z; sT[d0+ 7][il]=acc1.w;
      sT[d0+ 8][il]=acc2.x; sT[d0+ 9][il]=acc2.y; sT[d0+10][il]=acc2.z; sT[d0+11][il]=acc2.w;
      sT[d0+12][il]=acc3.x; sT[d0+13][il]=acc3.y; sT[d0+14][il]=acc3.z; sT[d0+15][il]=acc3.w;
    }
  }
  __syncthreads();

  const int ti = tid & 15, to = tid >> 4;
  f4 a0 = {0.f,0.f,0.f,0.f}, a1 = a0, a2 = a0, a3 = a0;
  if (BN) {
    // BN the aggregated rows: column d holds sum S_d; use sc_d*S_d + 6*sh_d.
    // Done here (post-sync) via the GEMM read path to keep the write path simple.
#pragma unroll 16
    for (int d = 0; d < 64; ++d) {
      const float scd = scl[d], shd6 = 6.f * shl[d];
      f4 sv = *(const f4*)&sT[d][4*ti];
      sv.x = sv.x * scd + shd6; sv.y = sv.y * scd + shd6;
      sv.z = sv.z * scd + shd6; sv.w = sv.w * scd + shd6;
      f4 wv = *(const f4*)&Wl[d][4*to];
      FMA16(sv, wv);
    }
  } else {
#pragma unroll 16
    for (int d = 0; d < 64; ++d) {
      f4 sv = *(const f4*)&sT[d][4*ti];
      f4 wv = *(const f4*)&Wl[d][4*to];
      FMA16(sv, wv);
    }
  }

  const float bs0 = 6.f*bb[4*to+0], bs1 = 6.f*bb[4*to+1], bs2 = 6.f*bb[4*to+2], bs3 = 6.f*bb[4*to+3];
  const float av0 = aa[4*to+0], av1 = aa[4*to+1], av2 = aa[4*to+2], av3 = aa[4*to+3];
  const float rs0 = BN ? scl[4*to+0] : 1.f, rs1 = BN ? scl[4*to+1] : 1.f;
  const float rs2 = BN ? scl[4*to+2] : 1.f, rs3 = BN ? scl[4*to+3] : 1.f;
  const float rh0 = BN ? shl[4*to+0] : 0.f, rh1 = BN ? shl[4*to+1] : 0.f;
  const float rh2 = BN ? shl[4*to+2] : 0.f, rh3 = BN ? shl[4*to+3] : 0.f;
  float p0 = 0.f, pp1 = 0.f, pp2 = 0.f, pp3 = 0.f;
#define CEPI(AR, r) { \
    const int i = base + 4*ti + (r); \
    f4 res = *((const f4*)(hIn + (size_t)i * 64) + to); \
    f4 ov; float v; \
    v = AR.x + bs0 + res.x*rs0 + rh0; v = v >= 0.f ? v : av0 * v; ov.x = v; p0  += v; \
    v = AR.y + bs1 + res.y*rs1 + rh1; v = v >= 0.f ? v : av1 * v; ov.y = v; pp1 += v; \
    v = AR.z + bs2 + res.z*rs2 + rh2; v = v >= 0.f ? v : av2 * v; ov.z = v; pp2 += v; \
    v = AR.w + bs3 + res.w*rs3 + rh3; v = v >= 0.f ? v : av3 * v; ov.w = v; pp3 += v; \
    *((f4*)(hOut + (size_t)i * 64) + to) = ov; }
  CEPI(a0, 0) CEPI(a1, 1) CEPI(a2, 2) CEPI(a3, 3)
#undef CEPI
  atomicAdd(&pool[4*to+0], p0);
  atomicAdd(&pool[4*to+1], pp1);
  atomicAdd(&pool[4*to+2], pp2);
  atomicAdd(&pool[4*to+3], pp3);
  __syncthreads();
  if (tid < 64) atomicAdd(&pooled[g * 320 + stageoff + tid], pool[tid]);
}

// ---------------- FFN head: one block per graph ----------------------------
__global__ __launch_bounds__(256) void kffn(const float* __restrict__ pooled,
    const float* __restrict__ W1, const float* __restrict__ b1,
    const float* __restrict__ W2, const float* __restrict__ b2,
    float* __restrict__ out) {
  __shared__ float pg[320];
  __shared__ float z1[320];
  __shared__ float red[4];
  const int g = blockIdx.x, tid = threadIdx.x;
  for (int i = tid; i < 320; i += 256) pg[i] = pooled[g * 320 + i];
  __syncthreads();
  for (int o = tid; o < 320; o += 256) {
    float acc = b1[o];
    for (int d = 0; d < 320; ++d) acc += pg[d] * W1[d * 320 + o];
    z1[o] = acc >= 0.f ? acc : 0.01f * acc;
  }
  __syncthreads();
  float p = 0.f;
  for (int o = tid; o < 320; o += 256) p += z1[o] * W2[o];
#pragma unroll
  for (int m = 32; m; m >>= 1) p += __shfl_xor(p, m, 64);
  if ((tid & 63) == 0) red[tid >> 6] = p;
  __syncthreads();
  if (tid == 0) out[g] = red[0] + red[1] + red[2] + red[3] + b2[0];
}

extern "C" void kernel_launch(void* const* d_in, const int* in_sizes, int n_in,
                              void* d_out, int out_size, void* d_ws, size_t ws_size,
                              hipStream_t stream) {
  const float* x        = (const float*)d_in[0];
  const float* pre_W1   = (const float*)d_in[2];
  const float* pre_b1   = (const float*)d_in[3];
  const float* pre_a1   = (const float*)d_in[4];
  const float* pre_W2   = (const float*)d_in[5];
  const float* pre_b2   = (const float*)d_in[6];
  const float* pre_a2   = (const float*)d_in[7];
  const float* bn_gamma = (const float*)d_in[8];
  const float* bn_beta  = (const float*)d_in[9];
  const float* act_a    = (const float*)d_in[10];
  const float* conv_W   = (const float*)d_in[11];
  const float* conv_b   = (const float*)d_in[12];
  const float* ffn_W1   = (const float*)d_in[13];
  const float* ffn_b1   = (const float*)d_in[14];
  const float* ffn_W2   = (const float*)d_in[15];
  const float* ffn_b2   = (const float*)d_in[16];
  float* out = (float*)d_out;

  float* ws = (float*)d_ws;
  float* hA = ws;                                   // N*64 floats (16 MB)
  float* hB = ws + 4194304;                         // N*64 floats (16 MB)
  // Aliases (stream-ordered): xbf2 on hB (dead before kconv1 writes hB),
  // sq3 on hA head (dead before kpre writes hA).
  ushort* xbf2 = (ushort*)hB;                       // N*128 bf16 hi/lo
  uint2*  sq3  = (uint2*)hA;                        // N uint2
  int*   nbr   = (int*)(ws + 8388608);              // N*6 ints
  float* stats = ws + 8388608 + 393216;
  float* gsq    = stats;                            // 64
  float* gsumg  = stats + 64;                       // 64*64
  float* scale  = stats + 64 + 4096;                // 64
  float* shift  = stats + 64 + 4096 + 64;           // 64
  float* pooled = stats + 64 + 4096 + 128;          // 64*320

  hipMemsetAsync(stats, 0, (64 + 4096 + 128 + 64 * 320) * sizeof(float), stream);

  kprep <<<16384, 256, 0, stream>>>(x, xbf2, sq3);
  kknn  <<<2048, 256, 0, stream>>>(xbf2, sq3, nbr);
  kpre  <<<1024, 256, 0, stream>>>(x, pre_W1, pre_b1, pre_a1, pre_W2, pre_b2, pre_a2,
                                   hA, gsumg, gsq);
  kfin  <<<64, 64, 0, stream>>>(gsumg, gsq, bn_gamma, bn_beta, scale, shift, pooled);
  kconv<1><<<1024, 256, 0, stream>>>(hA, hB, nbr, conv_W,         conv_b,       act_a, scale, shift, pooled, 64);
  kconv<0><<<1024, 256, 0, stream>>>(hB, hA, nbr, conv_W + 4096,  conv_b + 64,  act_a, scale, shift, pooled, 128);
  kconv<0><<<1024, 256, 0, stream>>>(hA, hB, nbr, conv_W + 8192,  conv_b + 128, act_a, scale, shift, pooled, 192);
  kconv<0><<<1024, 256, 0, stream>>>(hB, hA, nbr, conv_W + 12288, conv_b + 192, act_a, scale, shift, pooled, 256);
  kffn  <<<64, 256, 0, stream>>>(pooled, ffn_W1, ffn_b1, ffn_W2, ffn_b2, out);
}

// Round 9
// 300.894 us; speedup vs baseline: 3.0545x; 1.1273x over previous
//
#include <hip/hip_runtime.h>

// G=64 graphs, P=1024 nodes/graph, D=64 feat, K=6 knn. N=65536.
// fp32 in/out; KNN Gram via f16 MFMA + packed-key med3 top-6.

typedef float4 f4;
typedef unsigned short ushort;
typedef unsigned int uint;
typedef _Float16 f16;
typedef _Float16 f16x8 __attribute__((ext_vector_type(8)));
typedef float f32x16 __attribute__((ext_vector_type(16)));

#define FMA16(sv, wv) do { \
  a0.x += (sv).x*(wv).x; a0.y += (sv).x*(wv).y; a0.z += (sv).x*(wv).z; a0.w += (sv).x*(wv).w; \
  a1.x += (sv).y*(wv).x; a1.y += (sv).y*(wv).y; a1.z += (sv).y*(wv).z; a1.w += (sv).y*(wv).w; \
  a2.x += (sv).z*(wv).x; a2.y += (sv).z*(wv).y; a2.z += (sv).z*(wv).z; a2.w += (sv).z*(wv).w; \
  a3.x += (sv).w*(wv).x; a3.y += (sv).w*(wv).y; a3.z += (sv).w*(wv).z; a3.w += (sv).w*(wv).w; \
} while (0)

union HU { f16 h; ushort u; };
__device__ __forceinline__ ushort f2h_u(float f) { HU x; x.h = (f16)f; return x.u; }
__device__ __forceinline__ f16 u2h(ushort u) { HU x; x.u = u; return x.h; }

__device__ __forceinline__ uint med3u(uint a, uint b, uint c) {
  uint d;
  asm("v_med3_u32 %0, %1, %2, %3" : "=v"(d) : "v"(a), "v"(b), "v"(c));
  return d;
}

// 6-op insert of x into descending sorted m0>=...>=m5 (bottom-up, old values)
#define INSM(x) do { \
  m5 = med3u((x), m4, m5); \
  m4 = med3u((x), m3, m4); \
  m3 = med3u((x), m2, m3); \
  m2 = med3u((x), m1, m2); \
  m1 = med3u((x), m0, m1); \
  m0 = max(m0, (x)); \
} while (0)

// ---- KNN: block = 32 queries; 4 waves each scan 8 chunks of 32 candidates.
// score = q.c - 0.5||c||^2 (f16 inputs, f32 accum, +1536 bias via acc init);
// packed key = 22b fixed-point score | 10b (1023-idx).
__global__ __launch_bounds__(256, 4) void kknn(const ushort* __restrict__ xf16,
                                               const uint* __restrict__ sq2,
                                               int* __restrict__ nbr) {
  __shared__ uint skey[4][32][6];
  const int tid = threadIdx.x;
  const int lane = tid & 63;
  const int w = tid >> 6;
  const int q = lane & 31;
  const int h = lane >> 5;
  const int g = blockIdx.x >> 5;
  const int qtile = blockIdx.x & 31;
  const int gbase = g << 10;
  const int qloc = qtile * 32 + q;
  const int qglob = gbase + qloc;

  f16x8 Q0, Q1, Q2, Q3;
  {
    const ushort* qp = xf16 + (size_t)qglob * 64 + 8 * h;
    Q0 = *(const f16x8*)(qp);       Q1 = *(const f16x8*)(qp + 16);
    Q2 = *(const f16x8*)(qp + 32);  Q3 = *(const f16x8*)(qp + 48);
  }
  f16x8 Bsq = {(f16)0, (f16)0, (f16)0, (f16)0, (f16)0, (f16)0, (f16)0, (f16)0};
  if (h == 0) { Bsq[0] = (f16)1.0f; Bsq[1] = (f16)1.0f; }   // k-rows 0,1 = ones

  uint m0 = 0, m1 = 0, m2 = 0, m3 = 0, m4 = 0, m5 = 0;

  for (int cc = 0; cc < 8; ++cc) {
    const int cg = w * 8 + cc;                 // global chunk idx 0..31
    const int cb = gbase + cg * 32;
    const ushort* cp = xf16 + (size_t)(cb + q) * 64 + 8 * h;
    f16x8 A0 = *(const f16x8*)(cp);       f16x8 A1 = *(const f16x8*)(cp + 16);
    f16x8 A2 = *(const f16x8*)(cp + 32);  f16x8 A3 = *(const f16x8*)(cp + 48);
    uint sv = sq2[cb + q];
    f16x8 Asq = {(f16)0, (f16)0, (f16)0, (f16)0, (f16)0, (f16)0, (f16)0, (f16)0};
    if (h == 0) { Asq[0] = u2h((ushort)(sv & 0xffffu)); Asq[1] = u2h((ushort)(sv >> 16)); }

    f32x16 acc = {1536.f,1536.f,1536.f,1536.f,1536.f,1536.f,1536.f,1536.f,
                  1536.f,1536.f,1536.f,1536.f,1536.f,1536.f,1536.f,1536.f};
    acc = __builtin_amdgcn_mfma_f32_32x32x16_f16(A0, Q0, acc, 0, 0, 0);
    acc = __builtin_amdgcn_mfma_f32_32x32x16_f16(A1, Q1, acc, 0, 0, 0);
    acc = __builtin_amdgcn_mfma_f32_32x32x16_f16(A2, Q2, acc, 0, 0, 0);
    acc = __builtin_amdgcn_mfma_f32_32x32x16_f16(A3, Q3, acc, 0, 0, 0);
    acc = __builtin_amdgcn_mfma_f32_32x32x16_f16(Asq, Bsq, acc, 0, 0, 0);

    const int cl0 = cg * 32 + 4 * h;
    const uint kb = (uint)(1023 - cl0);        // key idx base (no borrow: pat <= kb&31)
    if (cg == qtile) {                         // diagonal chunk: mask self
#pragma unroll
      for (int r = 0; r < 16; ++r) {
        const int pat = (r & 3) + 8 * (r >> 2);
        uint u = __float_as_uint(acc[r]);
        uint key = (((u << 9) & 0xFFFFFC00u) | kb) - (uint)pat;
        if (cl0 + pat == qloc) key = 0u;
        INSM(key);
      }
    } else {
#pragma unroll
      for (int r = 0; r < 16; ++r) {
        const int pat = (r & 3) + 8 * (r >> 2);
        uint u = __float_as_uint(acc[r]);
        uint key = (((u << 9) & 0xFFFFFC00u) | kb) - (uint)pat;
        INSM(key);
      }
    }
  }

  // merge the two half-wave lists (snapshot partner first, then insert)
  {
    uint p0 = (uint)__shfl_xor((int)m0, 32, 64);
    uint p1 = (uint)__shfl_xor((int)m1, 32, 64);
    uint p2 = (uint)__shfl_xor((int)m2, 32, 64);
    uint p3 = (uint)__shfl_xor((int)m3, 32, 64);
    uint p4 = (uint)__shfl_xor((int)m4, 32, 64);
    uint p5 = (uint)__shfl_xor((int)m5, 32, 64);
    INSM(p0); INSM(p1); INSM(p2); INSM(p3); INSM(p4); INSM(p5);
  }
  if (h == 0) {
    skey[w][q][0] = m0; skey[w][q][1] = m1; skey[w][q][2] = m2;
    skey[w][q][3] = m3; skey[w][q][4] = m4; skey[w][q][5] = m5;
  }
  __syncthreads();

  if (tid < 32) {
    uint m0 = skey[0][tid][0], m1 = skey[0][tid][1], m2 = skey[0][tid][2];
    uint m3 = skey[0][tid][3], m4 = skey[0][tid][4], m5 = skey[0][tid][5];
#pragma unroll
    for (int ww = 1; ww < 4; ++ww)
#pragma unroll
      for (int k = 0; k < 6; ++k)
        INSM(skey[ww][tid][k]);
    const int ob = (gbase + qtile * 32 + tid) * 6;
    nbr[ob + 0] = gbase + 1023 - (int)(m0 & 1023u);
    nbr[ob + 1] = gbase + 1023 - (int)(m1 & 1023u);
    nbr[ob + 2] = gbase + 1023 - (int)(m2 & 1023u);
    nbr[ob + 3] = gbase + 1023 - (int)(m3 & 1023u);
    nbr[ob + 4] = gbase + 1023 - (int)(m4 & 1023u);
    nbr[ob + 5] = gbase + 1023 - (int)(m5 & 1023u);
  }
}

// ---- pre_nn (fused prep): 2x 64x64 GEMM + PReLU + f16(x) emit + norms + BN stats
__global__ __launch_bounds__(256) void kpre(const float* __restrict__ x,
    const float* __restrict__ W1, const float* __restrict__ b1, const float* __restrict__ p1,
    const float* __restrict__ W2, const float* __restrict__ b2, const float* __restrict__ p2,
    float* __restrict__ hpre, float* __restrict__ gsumg, float* __restrict__ gsq,
    ushort* __restrict__ xf16, uint* __restrict__ sq2) {
  __shared__ float xT[64][68];
  __shared__ float yT[64][68];
  __shared__ float W1l[64][64];
  __shared__ float W2l[64][64];
  __shared__ float bb1[64], aa1[64], bb2[64], aa2[64];
  __shared__ float ls[64], lq[64];
  __shared__ float ls2[64][4];
  const int tid = threadIdx.x;
  const int base = blockIdx.x * 64;
  const int g = base >> 10;
#pragma unroll
  for (int k = 0; k < 16; ++k) {
    int idx = tid + 256 * k;
    W1l[idx >> 6][idx & 63] = W1[idx];
    W2l[idx >> 6][idx & 63] = W2[idx];
  }
  if (tid < 64) {
    bb1[tid] = b1[tid]; aa1[tid] = p1[tid]; bb2[tid] = b2[tid]; aa2[tid] = p2[tid];
    ls[tid] = 0.f; lq[tid] = 0.f;
  }
  const int il = tid >> 2, qq = tid & 3;
  {
    const f4* src = (const f4*)(x + (size_t)(base + il) * 64) + qq * 4;
    float ssq = 0.f;
#pragma unroll
    for (int m = 0; m < 4; ++m) {
      f4 v = src[m];
      int d0 = qq * 16 + m * 4;
      xT[d0+0][il] = v.x; xT[d0+1][il] = v.y; xT[d0+2][il] = v.z; xT[d0+3][il] = v.w;
      ushort4 o4;
      o4.x = f2h_u(v.x); o4.y = f2h_u(v.y); o4.z = f2h_u(v.z); o4.w = f2h_u(v.w);
      *(ushort4*)(xf16 + (size_t)(base + il) * 64 + d0) = o4;
      ssq += v.x*v.x + v.y*v.y + v.z*v.z + v.w*v.w;
    }
    ls2[il][qq] = ssq;
  }
  __syncthreads();
  if (tid < 64) {   // finalize 2-term f16 norm for row base+tid
    float s = ls2[tid][0] + ls2[tid][1] + ls2[tid][2] + ls2[tid][3];
    float mm = -0.5f * s;
    ushort h1 = f2h_u(mm);
    HU t; t.u = h1;
    ushort h2 = f2h_u(mm - (float)t.h);
    sq2[base + tid] = (uint)h1 | ((uint)h2 << 16);
  }
  const int ti = tid & 15, to = tid >> 4;
  f4 a0 = {0.f,0.f,0.f,0.f}, a1 = a0, a2 = a0, a3 = a0;
#pragma unroll 16
  for (int d = 0; d < 64; ++d) {
    f4 sv = *(const f4*)&xT[d][4*ti];
    f4 wv = *(const f4*)&W1l[d][4*to];
    FMA16(sv, wv);
  }
#define EPI1(AR, r) { \
    const int row = 4*ti + (r); float v; \
    v = AR.x + bb1[4*to+0]; v = v >= 0.f ? v : aa1[4*to+0]*v; yT[4*to+0][row] = v; \
    v = AR.y + bb1[4*to+1]; v = v >= 0.f ? v : aa1[4*to+1]*v; yT[4*to+1][row] = v; \
    v = AR.z + bb1[4*to+2]; v = v >= 0.f ? v : aa1[4*to+2]*v; yT[4*to+2][row] = v; \
    v = AR.w + bb1[4*to+3]; v = v >= 0.f ? v : aa1[4*to+3]*v; yT[4*to+3][row] = v; }
  EPI1(a0, 0) EPI1(a1, 1) EPI1(a2, 2) EPI1(a3, 3)
#undef EPI1
  __syncthreads();
  a0.x=a0.y=a0.z=a0.w=0.f; a1=a0; a2=a0; a3=a0;
#pragma unroll 16
  for (int d = 0; d < 64; ++d) {
    f4 sv = *(const f4*)&yT[d][4*ti];
    f4 wv = *(const f4*)&W2l[d][4*to];
    FMA16(sv, wv);
  }
  float fs0=0.f,fs1=0.f,fs2=0.f,fs3=0.f, fq0=0.f,fq1=0.f,fq2=0.f,fq3=0.f;
#define EPI2(AR, r) { \
    const int i = base + 4*ti + (r); f4 ov; float v; \
    v = AR.x + bb2[4*to+0]; ov.x = v >= 0.f ? v : aa2[4*to+0]*v; \
    v = AR.y + bb2[4*to+1]; ov.y = v >= 0.f ? v : aa2[4*to+1]*v; \
    v = AR.z + bb2[4*to+2]; ov.z = v >= 0.f ? v : aa2[4*to+2]*v; \
    v = AR.w + bb2[4*to+3]; ov.w = v >= 0.f ? v : aa2[4*to+3]*v; \
    fs0 += ov.x; fq0 += ov.x*ov.x; fs1 += ov.y; fq1 += ov.y*ov.y; \
    fs2 += ov.z; fq2 += ov.z*ov.z; fs3 += ov.w; fq3 += ov.w*ov.w; \
    *((f4*)(hpre + (size_t)i * 64) + to) = ov; }
  EPI2(a0, 0) EPI2(a1, 1) EPI2(a2, 2) EPI2(a3, 3)
#undef EPI2
  atomicAdd(&ls[4*to+0], fs0); atomicAdd(&lq[4*to+0], fq0);
  atomicAdd(&ls[4*to+1], fs1); atomicAdd(&lq[4*to+1], fq1);
  atomicAdd(&ls[4*to+2], fs2); atomicAdd(&lq[4*to+2], fq2);
  atomicAdd(&ls[4*to+3], fs3); atomicAdd(&lq[4*to+3], fq3);
  __syncthreads();
  if (tid < 64) {
    atomicAdd(&gsumg[g * 64 + tid], ls[tid]);
    atomicAdd(&gsq[tid], lq[tid]);
  }
}

// ---- finalize BN: scale/shift + analytic stage-0 pool ---------------------
__global__ void kfin(const float* __restrict__ gsumg, const float* __restrict__ gsq,
                     const float* __restrict__ gamma, const float* __restrict__ beta,
                     float* __restrict__ scale, float* __restrict__ shift,
                     float* __restrict__ pooled) {
  const int g = blockIdx.x, f = threadIdx.x;
  float s = 0.f;
  for (int g2 = 0; g2 < 64; ++g2) s += gsumg[g2 * 64 + f];
  float mu = s * (1.f / 65536.f);
  float var = gsq[f] * (1.f / 65536.f) - mu * mu;
  float sc = gamma[f] * rsqrtf(var + 1e-5f);
  float sh = beta[f] - mu * sc;
  pooled[g * 320 + f] = sc * gsumg[g * 64 + f] + 1024.f * sh;
  if (g == 0) { scale[f] = sc; shift[f] = sh; }
}

// ---- conv layer: gather-sum (+inline BN on layer 1) + GEMM + PReLU + pool -
template <int BN>
__global__ __launch_bounds__(256) void kconv(const float* __restrict__ hIn,
    float* __restrict__ hOut, const int* __restrict__ nbr,
    const float* __restrict__ W, const float* __restrict__ bias,
    const float* __restrict__ act, const float* __restrict__ scale,
    const float* __restrict__ shift, float* __restrict__ pooled, int stageoff) {
  __shared__ float sT[64][68];
  __shared__ float Wl[64][64];
  __shared__ float bb[64], aa[64], pool[64];
  __shared__ float scl[64], shl[64];
  const int tid = threadIdx.x;
  const int base = blockIdx.x * 64;
  const int g = base >> 10;
#pragma unroll
  for (int k = 0; k < 16; ++k) { int idx = tid + 256 * k; Wl[idx >> 6][idx & 63] = W[idx]; }
  if (tid < 64) {
    bb[tid] = bias[tid]; aa[tid] = act[tid]; pool[tid] = 0.f;
    if (BN) { scl[tid] = scale[tid]; shl[tid] = shift[tid]; }
  }

  const int il = tid >> 2, qq = tid & 3;
  {
    f4 acc0 = {0.f,0.f,0.f,0.f}, acc1 = acc0, acc2 = acc0, acc3 = acc0;
    const int i = base + il;
#pragma unroll
    for (int k = 0; k < 6; ++k) {
      int j = nbr[i * 6 + k];
      const f4* hj = (const f4*)(hIn + (size_t)j * 64) + qq * 4;
      f4 v0 = hj[0], v1 = hj[1], v2 = hj[2], v3 = hj[3];
      acc0.x += v0.x; acc0.y += v0.y; acc0.z += v0.z; acc0.w += v0.w;
      acc1.x += v1.x; acc1.y += v1.y; acc1.z += v1.z; acc1.w += v1.w;
      acc2.x += v2.x; acc2.y += v2.y; acc2.z += v2.z; acc2.w += v2.w;
      acc3.x += v3.x; acc3.y += v3.y; acc3.z += v3.z; acc3.w += v3.w;
    }
    const int d0 = qq * 16;
    sT[d0+ 0][il]=acc0.x; sT[d0+ 1][il]=acc0.y; sT[d0+ 2][il]=acc0.z; sT[d0+ 3][il]=acc0.w;
    sT[d0+ 4][il]=acc1.x; sT[d0+ 5][il]=acc1.y; sT[d0+ 6][il]=acc1.z; sT[d0+ 7][il]=acc1.w;
    sT[d0+ 8][il]=acc2.x; sT[d0+ 9][il]=acc2.y; sT[d0+10][il]=acc2.z; sT[d0+11][il]=acc2.w;
    sT[d0+12][il]=acc3.x; sT[d0+13][il]=acc3.y; sT[d0+14][il]=acc3.z; sT[d0+15][il]=acc3.w;
  }
  __syncthreads();

  const int ti = tid & 15, to = tid >> 4;
  f4 a0 = {0.f,0.f,0.f,0.f}, a1 = a0, a2 = a0, a3 = a0;
  if (BN) {
    // column d of sT holds the 6-neighbor sum S_d -> BN'd: sc_d*S_d + 6*sh_d
#pragma unroll 16
    for (int d = 0; d < 64; ++d) {
      const float scd = scl[d], shd6 = 6.f * shl[d];
      f4 sv = *(const f4*)&sT[d][4*ti];
      sv.x = sv.x * scd + shd6; sv.y = sv.y * scd + shd6;
      sv.z = sv.z * scd + shd6; sv.w = sv.w * scd + shd6;
      f4 wv = *(const f4*)&Wl[d][4*to];
      FMA16(sv, wv);
    }
  } else {
#pragma unroll 16
    for (int d = 0; d < 64; ++d) {
      f4 sv = *(const f4*)&sT[d][4*ti];
      f4 wv = *(const f4*)&Wl[d][4*to];
      FMA16(sv, wv);
    }
  }

  const float bs0 = 6.f*bb[4*to+0], bs1 = 6.f*bb[4*to+1], bs2 = 6.f*bb[4*to+2], bs3 = 6.f*bb[4*to+3];
  const float av0 = aa[4*to+0], av1 = aa[4*to+1], av2 = aa[4*to+2], av3 = aa[4*to+3];
  const float rs0 = BN ? scl[4*to+0] : 1.f, rs1 = BN ? scl[4*to+1] : 1.f;
  const float rs2 = BN ? scl[4*to+2] : 1.f, rs3 = BN ? scl[4*to+3] : 1.f;
  const float rh0 = BN ? shl[4*to+0] : 0.f, rh1 = BN ? shl[4*to+1] : 0.f;
  const float rh2 = BN ? shl[4*to+2] : 0.f, rh3 = BN ? shl[4*to+3] : 0.f;
  float p0 = 0.f, pp1 = 0.f, pp2 = 0.f, pp3 = 0.f;
#define CEPI(AR, r) { \
    const int i = base + 4*ti + (r); \
    f4 res = *((const f4*)(hIn + (size_t)i * 64) + to); \
    f4 ov; float v; \
    v = AR.x + bs0 + res.x*rs0 + rh0; v = v >= 0.f ? v : av0 * v; ov.x = v; p0  += v; \
    v = AR.y + bs1 + res.y*rs1 + rh1; v = v >= 0.f ? v : av1 * v; ov.y = v; pp1 += v; \
    v = AR.z + bs2 + res.z*rs2 + rh2; v = v >= 0.f ? v : av2 * v; ov.z = v; pp2 += v; \
    v = AR.w + bs3 + res.w*rs3 + rh3; v = v >= 0.f ? v : av3 * v; ov.w = v; pp3 += v; \
    *((f4*)(hOut + (size_t)i * 64) + to) = ov; }
  CEPI(a0, 0) CEPI(a1, 1) CEPI(a2, 2) CEPI(a3, 3)
#undef CEPI
  atomicAdd(&pool[4*to+0], p0);
  atomicAdd(&pool[4*to+1], pp1);
  atomicAdd(&pool[4*to+2], pp2);
  atomicAdd(&pool[4*to+3], pp3);
  __syncthreads();
  if (tid < 64) atomicAdd(&pooled[g * 320 + stageoff + tid], pool[tid]);
}

// ---------------- FFN head: one block per graph ----------------------------
__global__ __launch_bounds__(256) void kffn(const float* __restrict__ pooled,
    const float* __restrict__ W1, const float* __restrict__ b1,
    const float* __restrict__ W2, const float* __restrict__ b2,
    float* __restrict__ out) {
  __shared__ float pg[320];
  __shared__ float z1[320];
  __shared__ float red[4];
  const int g = blockIdx.x, tid = threadIdx.x;
  for (int i = tid; i < 320; i += 256) pg[i] = pooled[g * 320 + i];
  __syncthreads();
  for (int o = tid; o < 320; o += 256) {
    float acc = b1[o];
    for (int d = 0; d < 320; ++d) acc += pg[d] * W1[d * 320 + o];
    z1[o] = acc >= 0.f ? acc : 0.01f * acc;
  }
  __syncthreads();
  float p = 0.f;
  for (int o = tid; o < 320; o += 256) p += z1[o] * W2[o];
#pragma unroll
  for (int m = 32; m; m >>= 1) p += __shfl_xor(p, m, 64);
  if ((tid & 63) == 0) red[tid >> 6] = p;
  __syncthreads();
  if (tid == 0) out[g] = red[0] + red[1] + red[2] + red[3] + b2[0];
}

extern "C" void kernel_launch(void* const* d_in, const int* in_sizes, int n_in,
                              void* d_out, int out_size, void* d_ws, size_t ws_size,
                              hipStream_t stream) {
  const float* x        = (const float*)d_in[0];
  const float* pre_W1   = (const float*)d_in[2];
  const float* pre_b1   = (const float*)d_in[3];
  const float* pre_a1   = (const float*)d_in[4];
  const float* pre_W2   = (const float*)d_in[5];
  const float* pre_b2   = (const float*)d_in[6];
  const float* pre_a2   = (const float*)d_in[7];
  const float* bn_gamma = (const float*)d_in[8];
  const float* bn_beta  = (const float*)d_in[9];
  const float* act_a    = (const float*)d_in[10];
  const float* conv_W   = (const float*)d_in[11];
  const float* conv_b   = (const float*)d_in[12];
  const float* ffn_W1   = (const float*)d_in[13];
  const float* ffn_b1   = (const float*)d_in[14];
  const float* ffn_W2   = (const float*)d_in[15];
  const float* ffn_b2   = (const float*)d_in[16];
  float* out = (float*)d_out;

  float* ws = (float*)d_ws;
  float* hA = ws;                                   // N*64 floats (16 MB)
  float* hB = ws + 4194304;                         // N*64 floats (16 MB)
  // Aliases on hB (dead before kconv1 writes hB): xf16 8MB + sq2 256KB.
  ushort* xf16 = (ushort*)hB;                       // N*64 f16
  uint*   sq2  = (uint*)(hB + 2097152);             // N uints (2-term f16 norm)
  int*   nbr   = (int*)(ws + 8388608);              // N*6 ints
  float* stats = ws + 8388608 + 393216;
  float* gsq    = stats;                            // 64
  float* gsumg  = stats + 64;                       // 64*64
  float* scale  = stats + 64 + 4096;                // 64
  float* shift  = stats + 64 + 4096 + 64;           // 64
  float* pooled = stats + 64 + 4096 + 128;          // 64*320

  hipMemsetAsync(stats, 0, (64 + 4096 + 128 + 64 * 320) * sizeof(float), stream);

  kpre  <<<1024, 256, 0, stream>>>(x, pre_W1, pre_b1, pre_a1, pre_W2, pre_b2, pre_a2,
                                   hA, gsumg, gsq, xf16, sq2);
  kknn  <<<2048, 256, 0, stream>>>(xf16, sq2, nbr);
  kfin  <<<64, 64, 0, stream>>>(gsumg, gsq, bn_gamma, bn_beta, scale, shift, pooled);
  kconv<1><<<1024, 256, 0, stream>>>(hA, hB, nbr, conv_W,         conv_b,       act_a, scale, shift, pooled, 64);
  kconv<0><<<1024, 256, 0, stream>>>(hB, hA, nbr, conv_W + 4096,  conv_b + 64,  act_a, scale, shift, pooled, 128);
  kconv<0><<<1024, 256, 0, stream>>>(hA, hB, nbr, conv_W + 8192,  conv_b + 128, act_a, scale, shift, pooled, 192);
  kconv<0><<<1024, 256, 0, stream>>>(hB, hA, nbr, conv_W + 12288, conv_b + 192, act_a, scale, shift, pooled, 256);
  kffn  <<<64, 256, 0, stream>>>(pooled, ffn_W1, ffn_b1, ffn_W2, ffn_b2, out);
}

// Round 10
// 244.677 us; speedup vs baseline: 3.7563x; 1.2298x over previous
//
#include <hip/hip_runtime.h>

// G=64 graphs, P=1024 nodes/graph, D=64 feat, K=6 knn. N=65536.
// fp32 in/out; KNN via f16 MFMA + med3 top-6; pre_nn/conv GEMMs via f16 MFMA;
// h buffers stored f16.

typedef float4 f4;
typedef unsigned short ushort;
typedef unsigned int uint;
typedef _Float16 f16;
typedef _Float16 f16x8 __attribute__((ext_vector_type(8)));
typedef float f32x16 __attribute__((ext_vector_type(16)));

#define Z16 {0.f,0.f,0.f,0.f,0.f,0.f,0.f,0.f,0.f,0.f,0.f,0.f,0.f,0.f,0.f,0.f}

union HU { f16 h; ushort u; };
__device__ __forceinline__ ushort f2h_u(float f) { HU x; x.h = (f16)f; return x.u; }
__device__ __forceinline__ f16 u2h(ushort u) { HU x; x.u = u; return x.h; }

__device__ __forceinline__ uint med3u(uint a, uint b, uint c) {
  uint d;
  asm("v_med3_u32 %0, %1, %2, %3" : "=v"(d) : "v"(a), "v"(b), "v"(c));
  return d;
}

// 6-op insert of x into descending sorted m0>=...>=m5
#define INSM(x) do { \
  m5 = med3u((x), m4, m5); \
  m4 = med3u((x), m3, m4); \
  m3 = med3u((x), m2, m3); \
  m2 = med3u((x), m1, m2); \
  m1 = med3u((x), m0, m1); \
  m0 = max(m0, (x)); \
} while (0)

// ---- weight prep: W1,W2,conv_W[0..3] -> f16 transposed [n][k] ------------
__global__ void kwprep(const float* __restrict__ W1, const float* __restrict__ W2,
                       const float* __restrict__ convW, ushort* __restrict__ wt) {
  const int m = blockIdx.x;
  const float* src = (m == 0) ? W1 : (m == 1) ? W2 : convW + (m - 2) * 4096;
  ushort* dst = wt + m * 4096;
  for (int i = threadIdx.x; i < 4096; i += 256) {
    int k = i >> 6, n = i & 63;
    dst[n * 64 + k] = f2h_u(src[i]);
  }
}

// ---- KNN: unchanged from round 9 (f16 MFMA + packed-key med3 top-6) ------
__global__ __launch_bounds__(256, 4) void kknn(const ushort* __restrict__ xf16,
                                               const uint* __restrict__ sq2,
                                               int* __restrict__ nbr) {
  __shared__ uint skey[4][32][6];
  const int tid = threadIdx.x;
  const int lane = tid & 63;
  const int w = tid >> 6;
  const int q = lane & 31;
  const int h = lane >> 5;
  const int g = blockIdx.x >> 5;
  const int qtile = blockIdx.x & 31;
  const int gbase = g << 10;
  const int qloc = qtile * 32 + q;
  const int qglob = gbase + qloc;

  f16x8 Q0, Q1, Q2, Q3;
  {
    const ushort* qp = xf16 + (size_t)qglob * 64 + 8 * h;
    Q0 = *(const f16x8*)(qp);       Q1 = *(const f16x8*)(qp + 16);
    Q2 = *(const f16x8*)(qp + 32);  Q3 = *(const f16x8*)(qp + 48);
  }
  f16x8 Bsq = {(f16)0, (f16)0, (f16)0, (f16)0, (f16)0, (f16)0, (f16)0, (f16)0};
  if (h == 0) { Bsq[0] = (f16)1.0f; Bsq[1] = (f16)1.0f; }

  uint m0 = 0, m1 = 0, m2 = 0, m3 = 0, m4 = 0, m5 = 0;

  for (int cc = 0; cc < 8; ++cc) {
    const int cg = w * 8 + cc;
    const int cb = gbase + cg * 32;
    const ushort* cp = xf16 + (size_t)(cb + q) * 64 + 8 * h;
    f16x8 A0 = *(const f16x8*)(cp);       f16x8 A1 = *(const f16x8*)(cp + 16);
    f16x8 A2 = *(const f16x8*)(cp + 32);  f16x8 A3 = *(const f16x8*)(cp + 48);
    uint sv = sq2[cb + q];
    f16x8 Asq = {(f16)0, (f16)0, (f16)0, (f16)0, (f16)0, (f16)0, (f16)0, (f16)0};
    if (h == 0) { Asq[0] = u2h((ushort)(sv & 0xffffu)); Asq[1] = u2h((ushort)(sv >> 16)); }

    f32x16 acc = {1536.f,1536.f,1536.f,1536.f,1536.f,1536.f,1536.f,1536.f,
                  1536.f,1536.f,1536.f,1536.f,1536.f,1536.f,1536.f,1536.f};
    acc = __builtin_amdgcn_mfma_f32_32x32x16_f16(A0, Q0, acc, 0, 0, 0);
    acc = __builtin_amdgcn_mfma_f32_32x32x16_f16(A1, Q1, acc, 0, 0, 0);
    acc = __builtin_amdgcn_mfma_f32_32x32x16_f16(A2, Q2, acc, 0, 0, 0);
    acc = __builtin_amdgcn_mfma_f32_32x32x16_f16(A3, Q3, acc, 0, 0, 0);
    acc = __builtin_amdgcn_mfma_f32_32x32x16_f16(Asq, Bsq, acc, 0, 0, 0);

    const int cl0 = cg * 32 + 4 * h;
    const uint kb = (uint)(1023 - cl0);
    if (cg == qtile) {
#pragma unroll
      for (int r = 0; r < 16; ++r) {
        const int pat = (r & 3) + 8 * (r >> 2);
        uint u = __float_as_uint(acc[r]);
        uint key = (((u << 9) & 0xFFFFFC00u) | kb) - (uint)pat;
        if (cl0 + pat == qloc) key = 0u;
        INSM(key);
      }
    } else {
#pragma unroll
      for (int r = 0; r < 16; ++r) {
        const int pat = (r & 3) + 8 * (r >> 2);
        uint u = __float_as_uint(acc[r]);
        uint key = (((u << 9) & 0xFFFFFC00u) | kb) - (uint)pat;
        INSM(key);
      }
    }
  }

  {
    uint p0 = (uint)__shfl_xor((int)m0, 32, 64);
    uint p1 = (uint)__shfl_xor((int)m1, 32, 64);
    uint p2 = (uint)__shfl_xor((int)m2, 32, 64);
    uint p3 = (uint)__shfl_xor((int)m3, 32, 64);
    uint p4 = (uint)__shfl_xor((int)m4, 32, 64);
    uint p5 = (uint)__shfl_xor((int)m5, 32, 64);
    INSM(p0); INSM(p1); INSM(p2); INSM(p3); INSM(p4); INSM(p5);
  }
  if (h == 0) {
    skey[w][q][0] = m0; skey[w][q][1] = m1; skey[w][q][2] = m2;
    skey[w][q][3] = m3; skey[w][q][4] = m4; skey[w][q][5] = m5;
  }
  __syncthreads();

  if (tid < 32) {
    uint m0 = skey[0][tid][0], m1 = skey[0][tid][1], m2 = skey[0][tid][2];
    uint m3 = skey[0][tid][3], m4 = skey[0][tid][4], m5 = skey[0][tid][5];
#pragma unroll
    for (int ww = 1; ww < 4; ++ww)
#pragma unroll
      for (int k = 0; k < 6; ++k)
        INSM(skey[ww][tid][k]);
    const int ob = (gbase + qtile * 32 + tid) * 6;
    nbr[ob + 0] = gbase + 1023 - (int)(m0 & 1023u);
    nbr[ob + 1] = gbase + 1023 - (int)(m1 & 1023u);
    nbr[ob + 2] = gbase + 1023 - (int)(m2 & 1023u);
    nbr[ob + 3] = gbase + 1023 - (int)(m3 & 1023u);
    nbr[ob + 4] = gbase + 1023 - (int)(m4 & 1023u);
    nbr[ob + 5] = gbase + 1023 - (int)(m5 & 1023u);
  }
}

// ---- pre_nn via f16 MFMA: 128 rows/block, 4 waves x 32 rows --------------
// Emits xf16 + sq2, h (f16, pre-BN), per-graph sums + global sumsq.
__global__ __launch_bounds__(256) void kpre(
    const float* __restrict__ x, const ushort* __restrict__ w1t,
    const float* __restrict__ b1, const float* __restrict__ p1,
    const ushort* __restrict__ w2t, const float* __restrict__ b2,
    const float* __restrict__ p2, ushort* __restrict__ hout,
    float* __restrict__ gsumg, float* __restrict__ gsq,
    ushort* __restrict__ xf16, uint* __restrict__ sq2) {
  __shared__ ushort tile[4][32][72];   // per-wave f16 bounce [node][feat], pad 72
  __shared__ float ls[64], lq[64];
  const int tid = threadIdx.x, lane = tid & 63, w = tid >> 6;
  const int q = lane & 31, h = lane >> 5;
  const int rbase = blockIdx.x * 128 + w * 32;
  const int row = rbase + q;
  const int g = blockIdx.x >> 3;
  if (tid < 64) { ls[tid] = 0.f; lq[tid] = 0.f; }
  __syncthreads();

  // load x slices -> A frags + xf16 + sumsq
  f16x8 Ax[4]; float ssq = 0.f;
  const float* xp = x + (size_t)row * 64 + 8 * h;
  ushort* xo = xf16 + (size_t)row * 64 + 8 * h;
#pragma unroll
  for (int ks = 0; ks < 4; ++ks) {
    f4 a = *(const f4*)(xp + 16 * ks);
    f4 b = *(const f4*)(xp + 16 * ks + 4);
    f16x8 f;
    f[0] = (f16)a.x; f[1] = (f16)a.y; f[2] = (f16)a.z; f[3] = (f16)a.w;
    f[4] = (f16)b.x; f[5] = (f16)b.y; f[6] = (f16)b.z; f[7] = (f16)b.w;
    Ax[ks] = f;
    *(f16x8*)(xo + 16 * ks) = f;
    ssq += a.x*a.x + a.y*a.y + a.z*a.z + a.w*a.w + b.x*b.x + b.y*b.y + b.z*b.z + b.w*b.w;
  }
  ssq += __shfl_xor(ssq, 32, 64);
  if (h == 0) {
    float mm = -0.5f * ssq;
    ushort u1 = f2h_u(mm); HU t1; t1.u = u1;
    ushort u2 = f2h_u(mm - (float)t1.h);
    sq2[row] = (uint)u1 | ((uint)u2 << 16);
  }

  // layer 1: h1 = prelu(x @ W1 + b1)
  f32x16 c0 = Z16, c1 = Z16;
#pragma unroll
  for (int ks = 0; ks < 4; ++ks) {
    f16x8 B0 = *(const f16x8*)(w1t + q * 64 + 16 * ks + 8 * h);
    f16x8 B1 = *(const f16x8*)(w1t + (q + 32) * 64 + 16 * ks + 8 * h);
    c0 = __builtin_amdgcn_mfma_f32_32x32x16_f16(Ax[ks], B0, c0, 0, 0, 0);
    c1 = __builtin_amdgcn_mfma_f32_32x32x16_f16(Ax[ks], B1, c1, 0, 0, 0);
  }
  {
    const float bb0 = b1[q], aa0 = p1[q], bb1 = b1[q + 32], aa1 = p1[q + 32];
#pragma unroll
    for (int r = 0; r < 16; ++r) {
      const int nd = (r & 3) + 8 * (r >> 2) + 4 * h;
      float v0 = c0[r] + bb0; v0 = v0 >= 0.f ? v0 : aa0 * v0;
      float v1 = c1[r] + bb1; v1 = v1 >= 0.f ? v1 : aa1 * v1;
      tile[w][nd][q] = f2h_u(v0);
      tile[w][nd][q + 32] = f2h_u(v1);
    }
  }
  // read back h1 as A frags (same-wave LDS, in-order)
  f16x8 Ah[4];
#pragma unroll
  for (int ks = 0; ks < 4; ++ks)
    Ah[ks] = *(const f16x8*)&tile[w][q][16 * ks + 8 * h];

  // layer 2: h = prelu(h1 @ W2 + b2); stats on rounded values
  f32x16 d0 = Z16, d1 = Z16;
#pragma unroll
  for (int ks = 0; ks < 4; ++ks) {
    f16x8 B0 = *(const f16x8*)(w2t + q * 64 + 16 * ks + 8 * h);
    f16x8 B1 = *(const f16x8*)(w2t + (q + 32) * 64 + 16 * ks + 8 * h);
    d0 = __builtin_amdgcn_mfma_f32_32x32x16_f16(Ah[ks], B0, d0, 0, 0, 0);
    d1 = __builtin_amdgcn_mfma_f32_32x32x16_f16(Ah[ks], B1, d1, 0, 0, 0);
  }
  {
    const float bb0 = b2[q], aa0 = p2[q], bb1 = b2[q + 32], aa1 = p2[q + 32];
    float s0 = 0.f, q0 = 0.f, s1 = 0.f, q1 = 0.f;
#pragma unroll
    for (int r = 0; r < 16; ++r) {
      const int nd = (r & 3) + 8 * (r >> 2) + 4 * h;
      float v0 = d0[r] + bb0; v0 = v0 >= 0.f ? v0 : aa0 * v0;
      float v1 = d1[r] + bb1; v1 = v1 >= 0.f ? v1 : aa1 * v1;
      ushort u0 = f2h_u(v0), u1 = f2h_u(v1);
      HU t0, t1; t0.u = u0; t1.u = u1;
      float r0 = (float)t0.h, r1 = (float)t1.h;      // stats on stored values
      s0 += r0; q0 += r0 * r0; s1 += r1; q1 += r1 * r1;
      tile[w][nd][q] = u0;
      tile[w][nd][q + 32] = u1;
    }
    s0 += __shfl_xor(s0, 32, 64); q0 += __shfl_xor(q0, 32, 64);
    s1 += __shfl_xor(s1, 32, 64); q1 += __shfl_xor(q1, 32, 64);
    if (h == 0) {
      atomicAdd(&ls[q], s0); atomicAdd(&lq[q], q0);
      atomicAdd(&ls[q + 32], s1); atomicAdd(&lq[q + 32], q1);
    }
  }
  // store h f16 (row-major readback)
  ushort* ho = hout + (size_t)row * 64 + 8 * h;
#pragma unroll
  for (int ks = 0; ks < 4; ++ks) {
    f16x8 v = *(const f16x8*)&tile[w][q][16 * ks + 8 * h];
    *(f16x8*)(ho + 16 * ks) = v;
  }
  __syncthreads();
  if (tid < 64) {
    atomicAdd(&gsumg[g * 64 + tid], ls[tid]);
    atomicAdd(&gsq[tid], lq[tid]);
  }
}

// ---- finalize BN: scale/shift + analytic stage-0 pool ---------------------
__global__ void kfin(const float* __restrict__ gsumg, const float* __restrict__ gsq,
                     const float* __restrict__ gamma, const float* __restrict__ beta,
                     float* __restrict__ scale, float* __restrict__ shift,
                     float* __restrict__ pooled) {
  const int g = blockIdx.x, f = threadIdx.x;
  float s = 0.f;
  for (int g2 = 0; g2 < 64; ++g2) s += gsumg[g2 * 64 + f];
  float mu = s * (1.f / 65536.f);
  float var = gsq[f] * (1.f / 65536.f) - mu * mu;
  float sc = gamma[f] * rsqrtf(var + 1e-5f);
  float sh = beta[f] - mu * sc;
  pooled[g * 320 + f] = sc * gsumg[g * 64 + f] + 1024.f * sh;
  if (g == 0) { scale[f] = sc; shift[f] = sh; }
}

// ---- conv layer (f16): gather(+BN) -> MFMA -> bounce -> residual epilogue -
template <int BN>
__global__ __launch_bounds__(256) void kconv(
    const ushort* __restrict__ hIn, ushort* __restrict__ hOut,
    const int* __restrict__ nbr, const ushort* __restrict__ wt,
    const float* __restrict__ bias, const float* __restrict__ act,
    const float* __restrict__ scale, const float* __restrict__ shift,
    float* __restrict__ pooled, int stageoff) {
  __shared__ ushort tile[4][32][72];
  __shared__ float pool[64];
  const int tid = threadIdx.x, lane = tid & 63, w = tid >> 6;
  const int q = lane & 31, h = lane >> 5;
  const int nbase = blockIdx.x * 128 + w * 32;
  const int node = nbase + q;
  const int g = blockIdx.x >> 3;
  if (tid < 64) pool[tid] = 0.f;
  __syncthreads();

  const int* np = nbr + (size_t)node * 6;
  const int j0 = np[0], j1 = np[1], j2 = np[2], j3 = np[3], j4 = np[4], j5 = np[5];

  f16x8 Af[4];
#pragma unroll
  for (int ks = 0; ks < 4; ++ks) {
    const int off = 16 * ks + 8 * h;
    float s0=0.f,s1=0.f,s2=0.f,s3=0.f,s4=0.f,s5=0.f,s6=0.f,s7=0.f;
#define ACC6(J) { f16x8 v = *(const f16x8*)(hIn + (size_t)(J) * 64 + off); \
    s0 += (float)v[0]; s1 += (float)v[1]; s2 += (float)v[2]; s3 += (float)v[3]; \
    s4 += (float)v[4]; s5 += (float)v[5]; s6 += (float)v[6]; s7 += (float)v[7]; }
    ACC6(j0) ACC6(j1) ACC6(j2) ACC6(j3) ACC6(j4) ACC6(j5)
#undef ACC6
    if (BN) {
      f4 sa = *(const f4*)(scale + off), sb = *(const f4*)(scale + off + 4);
      f4 ha = *(const f4*)(shift + off), hb = *(const f4*)(shift + off + 4);
      s0 = s0*sa.x + 6.f*ha.x; s1 = s1*sa.y + 6.f*ha.y;
      s2 = s2*sa.z + 6.f*ha.z; s3 = s3*sa.w + 6.f*ha.w;
      s4 = s4*sb.x + 6.f*hb.x; s5 = s5*sb.y + 6.f*hb.y;
      s6 = s6*sb.z + 6.f*hb.z; s7 = s7*sb.w + 6.f*hb.w;
    }
    f16x8 f;
    f[0]=(f16)s0; f[1]=(f16)s1; f[2]=(f16)s2; f[3]=(f16)s3;
    f[4]=(f16)s4; f[5]=(f16)s5; f[6]=(f16)s6; f[7]=(f16)s7;
    Af[ks] = f;
  }

  f32x16 c0 = Z16, c1 = Z16;
#pragma unroll
  for (int ks = 0; ks < 4; ++ks) {
    f16x8 B0 = *(const f16x8*)(wt + q * 64 + 16 * ks + 8 * h);
    f16x8 B1 = *(const f16x8*)(wt + (q + 32) * 64 + 16 * ks + 8 * h);
    c0 = __builtin_amdgcn_mfma_f32_32x32x16_f16(Af[ks], B0, c0, 0, 0, 0);
    c1 = __builtin_amdgcn_mfma_f32_32x32x16_f16(Af[ks], B1, c1, 0, 0, 0);
  }
  // bounce z = acc + 6b to LDS (f16)
  {
    const float bb0 = 6.f * bias[q], bb1 = 6.f * bias[q + 32];
#pragma unroll
    for (int r = 0; r < 16; ++r) {
      const int nd = (r & 3) + 8 * (r >> 2) + 4 * h;
      tile[w][nd][q] = f2h_u(c0[r] + bb0);
      tile[w][nd][q + 32] = f2h_u(c1[r] + bb1);
    }
  }

  // epilogue remap: lane = a*8+b -> 4 nodes (4a..4a+4) x 8 feats (8b..8b+8)
  const int a = lane >> 3, b = lane & 7;
  f4 aa0 = *(const f4*)(act + 8 * b), aa1 = *(const f4*)(act + 8 * b + 4);
  f4 rs0, rs1, rh0, rh1;
  if (BN) {
    rs0 = *(const f4*)(scale + 8 * b); rs1 = *(const f4*)(scale + 8 * b + 4);
    rh0 = *(const f4*)(shift + 8 * b); rh1 = *(const f4*)(shift + 8 * b + 4);
  }
  f4 ps0 = {0.f,0.f,0.f,0.f}, ps1 = ps0;
#pragma unroll
  for (int r = 0; r < 4; ++r) {
    const int nd = 4 * a + r;
    const size_t gn = (size_t)(nbase + nd) * 64 + 8 * b;
    f16x8 z = *(const f16x8*)&tile[w][nd][8 * b];
    f16x8 ro = *(const f16x8*)(hIn + gn);
    float v0 = (float)z[0] + (BN ? rs0.x * (float)ro[0] + rh0.x : (float)ro[0]);
    float v1 = (float)z[1] + (BN ? rs0.y * (float)ro[1] + rh0.y : (float)ro[1]);
    float v2 = (float)z[2] + (BN ? rs0.z * (float)ro[2] + rh0.z : (float)ro[2]);
    float v3 = (float)z[3] + (BN ? rs0.w * (float)ro[3] + rh0.w : (float)ro[3]);
    float v4 = (float)z[4] + (BN ? rs1.x * (float)ro[4] + rh1.x : (float)ro[4]);
    float v5 = (float)z[5] + (BN ? rs1.y * (float)ro[5] + rh1.y : (float)ro[5]);
    float v6 = (float)z[6] + (BN ? rs1.z * (float)ro[6] + rh1.z : (float)ro[6]);
    float v7 = (float)z[7] + (BN ? rs1.w * (float)ro[7] + rh1.w : (float)ro[7]);
    v0 = v0 >= 0.f ? v0 : aa0.x * v0;  v1 = v1 >= 0.f ? v1 : aa0.y * v1;
    v2 = v2 >= 0.f ? v2 : aa0.z * v2;  v3 = v3 >= 0.f ? v3 : aa0.w * v3;
    v4 = v4 >= 0.f ? v4 : aa1.x * v4;  v5 = v5 >= 0.f ? v5 : aa1.y * v5;
    v6 = v6 >= 0.f ? v6 : aa1.z * v6;  v7 = v7 >= 0.f ? v7 : aa1.w * v7;
    ps0.x += v0; ps0.y += v1; ps0.z += v2; ps0.w += v3;
    ps1.x += v4; ps1.y += v5; ps1.z += v6; ps1.w += v7;
    f16x8 o;
    o[0]=(f16)v0; o[1]=(f16)v1; o[2]=(f16)v2; o[3]=(f16)v3;
    o[4]=(f16)v4; o[5]=(f16)v5; o[6]=(f16)v6; o[7]=(f16)v7;
    *(f16x8*)(hOut + gn) = o;
  }
  // reduce node-partials across a (lane bits 3,4,5)
#pragma unroll
  for (int m = 8; m <= 32; m <<= 1) {
    ps0.x += __shfl_xor(ps0.x, m, 64); ps0.y += __shfl_xor(ps0.y, m, 64);
    ps0.z += __shfl_xor(ps0.z, m, 64); ps0.w += __shfl_xor(ps0.w, m, 64);
    ps1.x += __shfl_xor(ps1.x, m, 64); ps1.y += __shfl_xor(ps1.y, m, 64);
    ps1.z += __shfl_xor(ps1.z, m, 64); ps1.w += __shfl_xor(ps1.w, m, 64);
  }
  if (a == 0) {
    atomicAdd(&pool[8 * b + 0], ps0.x); atomicAdd(&pool[8 * b + 1], ps0.y);
    atomicAdd(&pool[8 * b + 2], ps0.z); atomicAdd(&pool[8 * b + 3], ps0.w);
    atomicAdd(&pool[8 * b + 4], ps1.x); atomicAdd(&pool[8 * b + 5], ps1.y);
    atomicAdd(&pool[8 * b + 6], ps1.z); atomicAdd(&pool[8 * b + 7], ps1.w);
  }
  __syncthreads();
  if (tid < 64) atomicAdd(&pooled[g * 320 + stageoff + tid], pool[tid]);
}

// ---------------- FFN head: one block per graph ----------------------------
__global__ __launch_bounds__(256) void kffn(const float* __restrict__ pooled,
    const float* __restrict__ W1, const float* __restrict__ b1,
    const float* __restrict__ W2, const float* __restrict__ b2,
    float* __restrict__ out) {
  __shared__ float pg[320];
  __shared__ float z1[320];
  __shared__ float red[4];
  const int g = blockIdx.x, tid = threadIdx.x;
  for (int i = tid; i < 320; i += 256) pg[i] = pooled[g * 320 + i];
  __syncthreads();
  for (int o = tid; o < 320; o += 256) {
    float acc = b1[o];
    for (int d = 0; d < 320; ++d) acc += pg[d] * W1[d * 320 + o];
    z1[o] = acc >= 0.f ? acc : 0.01f * acc;
  }
  __syncthreads();
  float p = 0.f;
  for (int o = tid; o < 320; o += 256) p += z1[o] * W2[o];
#pragma unroll
  for (int m = 32; m; m >>= 1) p += __shfl_xor(p, m, 64);
  if ((tid & 63) == 0) red[tid >> 6] = p;
  __syncthreads();
  if (tid == 0) out[g] = red[0] + red[1] + red[2] + red[3] + b2[0];
}

extern "C" void kernel_launch(void* const* d_in, const int* in_sizes, int n_in,
                              void* d_out, int out_size, void* d_ws, size_t ws_size,
                              hipStream_t stream) {
  const float* x        = (const float*)d_in[0];
  const float* pre_W1   = (const float*)d_in[2];
  const float* pre_b1   = (const float*)d_in[3];
  const float* pre_a1   = (const float*)d_in[4];
  const float* pre_W2   = (const float*)d_in[5];
  const float* pre_b2   = (const float*)d_in[6];
  const float* pre_a2   = (const float*)d_in[7];
  const float* bn_gamma = (const float*)d_in[8];
  const float* bn_beta  = (const float*)d_in[9];
  const float* act_a    = (const float*)d_in[10];
  const float* conv_W   = (const float*)d_in[11];
  const float* conv_b   = (const float*)d_in[12];
  const float* ffn_W1   = (const float*)d_in[13];
  const float* ffn_b1   = (const float*)d_in[14];
  const float* ffn_W2   = (const float*)d_in[15];
  const float* ffn_b2   = (const float*)d_in[16];
  float* out = (float*)d_out;

  ushort* hA16 = (ushort*)d_ws;                     // N*64 f16 (8 MB)
  ushort* hB16 = hA16 + 4194304;                    // N*64 f16 (8 MB)
  ushort* xf16 = hB16 + 4194304;                    // N*64 f16 (8 MB)
  uint*   sq2  = (uint*)(xf16 + 4194304);           // N
  int*    nbr  = (int*)(sq2 + 65536);               // N*6
  ushort* wt   = (ushort*)(nbr + 393216);           // 6*4096 f16 (48 KB)
  float* stats = (float*)(wt + 24576);
  float* gsq    = stats;                            // 64
  float* gsumg  = stats + 64;                       // 64*64
  float* scale  = stats + 64 + 4096;                // 64
  float* shift  = stats + 64 + 4096 + 64;           // 64
  float* pooled = stats + 64 + 4096 + 128;          // 64*320

  hipMemsetAsync(stats, 0, (64 + 4096 + 128 + 64 * 320) * sizeof(float), stream);

  kwprep<<<6, 256, 0, stream>>>(pre_W1, pre_W2, conv_W, wt);
  kpre  <<<512, 256, 0, stream>>>(x, wt, pre_b1, pre_a1, wt + 4096, pre_b2, pre_a2,
                                  hA16, gsumg, gsq, xf16, sq2);
  kknn  <<<2048, 256, 0, stream>>>(xf16, sq2, nbr);
  kfin  <<<64, 64, 0, stream>>>(gsumg, gsq, bn_gamma, bn_beta, scale, shift, pooled);
  kconv<1><<<512, 256, 0, stream>>>(hA16, hB16, nbr, wt + 2*4096, conv_b,       act_a, scale, shift, pooled, 64);
  kconv<0><<<512, 256, 0, stream>>>(hB16, hA16, nbr, wt + 3*4096, conv_b + 64,  act_a, scale, shift, pooled, 128);
  kconv<0><<<512, 256, 0, stream>>>(hA16, hB16, nbr, wt + 4*4096, conv_b + 128, act_a, scale, shift, pooled, 192);
  kconv<0><<<512, 256, 0, stream>>>(hB16, hA16, nbr, wt + 5*4096, conv_b + 192, act_a, scale, shift, pooled, 256);
  kffn  <<<64, 256, 0, stream>>>(pooled, ffn_W1, ffn_b1, ffn_W2, ffn_b2, out);
}